// Round 7
// baseline (2180.295 us; speedup 1.0000x reference)
//
#include <hip/hip_runtime.h>
#include <hip/hip_fp16.h>
#include <math.h>

#define N 2048
#define DIM 128
#define CAP (N*64)
#define LOGN 7.6246189861593985f
#define SSCALE 16384.0f
#define ISCALE 6.103515625e-05f   // 1/16384

typedef unsigned long long u64;
typedef unsigned int u32;

// ---------------------------------------------------------------- precompute

// inter = exp(-(A @ B^T)); per-block partial sums -> k1p
__global__ __launch_bounds__(256) void k_gemm_inter(
    const float* __restrict__ A, const float* __restrict__ B,
    float* __restrict__ O, double* __restrict__ k1p) {
  __shared__ __align__(16) float As[64][65];
  __shared__ __align__(16) float Bs[64][65];
  __shared__ float red[256];
  const int t = threadIdx.x;
  const int i0 = blockIdx.y * 64, j0 = blockIdx.x * 64;
  const int tx = t & 15, ty = t >> 4;
  float acc[4][4] = {};
  for (int kk = 0; kk < DIM; kk += 64) {
    if (kk) __syncthreads();
    for (int q = t; q < 64 * 16; q += 256) {
      int row = q >> 4, k4 = (q & 15) << 2;
      float4 av = *(const float4*)&A[(size_t)(i0 + row) * DIM + kk + k4];
      As[k4 + 0][row] = av.x; As[k4 + 1][row] = av.y;
      As[k4 + 2][row] = av.z; As[k4 + 3][row] = av.w;
      float4 bv = *(const float4*)&B[(size_t)(j0 + row) * DIM + kk + k4];
      Bs[k4 + 0][row] = bv.x; Bs[k4 + 1][row] = bv.y;
      Bs[k4 + 2][row] = bv.z; Bs[k4 + 3][row] = bv.w;
    }
    __syncthreads();
    #pragma unroll 4
    for (int k = 0; k < 64; ++k) {
      float av[4], bv[4];
      #pragma unroll
      for (int d = 0; d < 4; ++d) { av[d] = As[k][ty * 4 + d]; bv[d] = Bs[k][tx * 4 + d]; }
      #pragma unroll
      for (int di = 0; di < 4; ++di)
        #pragma unroll
        for (int dj = 0; dj < 4; ++dj)
          acc[di][dj] = fmaf(av[di], bv[dj], acc[di][dj]);
    }
  }
  float psum = 0.f;
  #pragma unroll
  for (int di = 0; di < 4; ++di)
    #pragma unroll
    for (int dj = 0; dj < 4; ++dj) {
      float vv = __expf(-acc[di][dj]);
      O[(size_t)(i0 + ty * 4 + di) * N + (j0 + tx * 4 + dj)] = vv;
      psum += vv;
    }
  red[t] = psum; __syncthreads();
  for (int off = 128; off; off >>= 1) { if (t < off) red[t] += red[t + off]; __syncthreads(); }
  if (t == 0) k1p[blockIdx.y * 32 + blockIdx.x] = (double)red[0];
}

__global__ __launch_bounds__(256) void k_count(const float* __restrict__ adj, int* __restrict__ cnt) {
  int i = blockIdx.x * 4 + (threadIdx.x >> 6);
  int lane = threadIdx.x & 63;
  const float* row = adj + (size_t)i * N;
  int c = 0;
  for (int j = lane; j < N; j += 64) c += (row[j] != 0.f) ? 1 : 0;
  for (int off = 32; off; off >>= 1) c += __shfl_down(c, off);
  if (lane == 0) cnt[i] = c;
}

__global__ __launch_bounds__(256) void k_scan(const int* __restrict__ cnt, int* __restrict__ rp) {
  __shared__ int sums[256];
  int t = threadIdx.x;
  int local[8]; int run = 0;
  int base = t * 8;
  #pragma unroll
  for (int k = 0; k < 8; ++k) { local[k] = run; run += cnt[base + k]; }
  sums[t] = run; __syncthreads();
  for (int off = 1; off < 256; off <<= 1) {
    int val = (t >= off) ? sums[t - off] : 0;
    __syncthreads();
    sums[t] += val;
    __syncthreads();
  }
  int pre = (t == 0) ? 0 : sums[t - 1];
  #pragma unroll
  for (int k = 0; k < 8; ++k) rp[base + k] = pre + local[k];
  if (t == 255) rp[N] = sums[255];
}

__global__ __launch_bounds__(256) void k_fill(const float* __restrict__ adj, const int* __restrict__ rp,
                                              int* __restrict__ cols, int* __restrict__ rows) {
  int i = blockIdx.x * 4 + (threadIdx.x >> 6);
  int lane = threadIdx.x & 63;
  const float* row = adj + (size_t)i * N;
  int pos = rp[i];
  for (int j0 = 0; j0 < N; j0 += 64) {
    bool p = row[j0 + lane] != 0.f;
    u64 mask = __ballot(p);
    if (p) {
      int off = __popcll(mask & ((1ull << lane) - 1ull));
      cols[pos + off] = j0 + lane;
      rows[pos + off] = i;
    }
    pos += __popcll(mask);
  }
}

// vals[p] = exp(-dot(emb[rows[p]], emb[cols[p]])), grid-stride over nnz
__global__ __launch_bounds__(256) void k_vals(const int* __restrict__ rp, const int* __restrict__ rows,
                                              const int* __restrict__ cols, float* __restrict__ vals,
                                              const float* __restrict__ emb) {
  int lane = threadIdx.x & 63;
  int total = rp[N];
  for (int p = blockIdx.x * 4 + (threadIdx.x >> 6); p < total; p += 8192) {
    int i = rows[p], k = cols[p];
    const float* ei = emb + (size_t)i * DIM;
    const float* ek = emb + (size_t)k * DIM;
    float s = ei[lane] * ek[lane] + ei[lane + 64] * ek[lane + 64];
    for (int off = 32; off; off >>= 1) s += __shfl_down(s, off);
    if (lane == 0) vals[p] = __expf(-s);
  }
}

__global__ __launch_bounds__(256) void k_rowstats(const int* __restrict__ rp, const float* __restrict__ vals,
                                                  float* __restrict__ rs, float* __restrict__ rsq) {
  int i = blockIdx.x * 4 + (threadIdx.x >> 6);
  int lane = threadIdx.x & 63;
  int p0 = rp[i], p1 = rp[i + 1];
  float s1 = 0.f, s2 = 0.f;
  for (int p = p0 + lane; p < p1; p += 64) { float w = vals[p]; s1 += w; s2 += w * w; }
  for (int off = 32; off; off >>= 1) { s1 += __shfl_down(s1, off); s2 += __shfl_down(s2, off); }
  if (lane == 0) { rs[i] = s1; rsq[i] = s2; }
}

// ---------------------------------------------------------------- spmm (fp16-scaled input)
template<bool OUT_HALF>
__global__ __launch_bounds__(256) void k_spmmt(const int* __restrict__ rp, const int* __restrict__ cols,
                                               const float* __restrict__ vals, const __half* __restrict__ S,
                                               __half* __restrict__ OutH, float* __restrict__ OutF) {
  __shared__ int winc[1024];
  __shared__ float winv[1024];
  __shared__ int rb[9];
  const int t = threadIdx.x;
  const int tile = blockIdx.x & 7;
  const int c = tile * 256 + t;
  const int i0 = (blockIdx.x >> 3) * 8;
  const int p0 = rp[i0];
  if (t < 9) rb[t] = rp[i0 + t] - p0;
  __syncthreads();
  const int nn = rb[8];
  for (int k = t; k < nn; k += 256) {
    winc[k] = cols[p0 + k] << 11;     // *N
    winv[k] = vals[p0 + k];
  }
  __syncthreads();
  float a[8];
  #pragma unroll
  for (int r = 0; r < 8; ++r) {
    int pe = rb[r + 1];
    int p = rb[r];
    float a0 = 0.f, a1 = 0.f, a2 = 0.f, a3 = 0.f;
    for (; p + 3 < pe; p += 4) {
      a0 = fmaf(winv[p],     __half2float(S[winc[p]     + c]), a0);
      a1 = fmaf(winv[p + 1], __half2float(S[winc[p + 1] + c]), a1);
      a2 = fmaf(winv[p + 2], __half2float(S[winc[p + 2] + c]), a2);
      a3 = fmaf(winv[p + 3], __half2float(S[winc[p + 3] + c]), a3);
    }
    for (; p < pe; ++p) a0 = fmaf(winv[p], __half2float(S[winc[p] + c]), a0);
    a[r] = (a0 + a1) + (a2 + a3);
  }
  size_t ob = (size_t)(tile * 256 + t) * N + i0;
  if (OUT_HALF) {
    __half2 h0 = __halves2half2(__float2half_rn(a[0]), __float2half_rn(a[1]));
    __half2 h1 = __halves2half2(__float2half_rn(a[2]), __float2half_rn(a[3]));
    __half2 h2 = __halves2half2(__float2half_rn(a[4]), __float2half_rn(a[5]));
    __half2 h3 = __halves2half2(__float2half_rn(a[6]), __float2half_rn(a[7]));
    uint4 pk;
    pk.x = *(u32*)&h0; pk.y = *(u32*)&h1; pk.z = *(u32*)&h2; pk.w = *(u32*)&h3;
    *(uint4*)&OutH[ob] = pk;
  } else {
    *(float4*)&OutF[ob]     = make_float4(a[0], a[1], a[2], a[3]);
    *(float4*)&OutF[ob + 4] = make_float4(a[4], a[5], a[6], a[7]);
  }
}

// ---------------------------------------------------------------- prep
// mode 0: t==0 analytic;  mode 1: general;  mode 2: final raw pa/pb
// Also zeroes the 5 column-sum buffers Call[5*N] (modes 0/1).
__global__ __launch_bounds__(256) void k_prep(
    int mode,
    const int* __restrict__ rp1, const int* __restrict__ cols1, const float* __restrict__ vals1,
    const int* __restrict__ rp2, const int* __restrict__ cols2, const float* __restrict__ vals2,
    const float* __restrict__ r1sq, const float* __restrict__ rs1,
    const float* __restrict__ r2sq, const float* __restrict__ rs2,
    const float* __restrict__ as_, const float* __restrict__ bs_,
    const float* __restrict__ lamp,
    float* __restrict__ Ai, float* __restrict__ Bj, float* __restrict__ RLi,
    float* __restrict__ Call) {
  int g = blockIdx.x * 256 + threadIdx.x;
  float lam = *lamp;
  if (mode == 0) {
    float f = 0.00048828125f - lam * 2048.f;            // 2048*(s0 - lam)
    if (g < N) {
      Ai[g] = -2000.f * r1sq[g] * f;
      RLi[g] = 4000.f * rs1[g] * (2.384185791015625e-07f - lam);
    } else if (g < 2 * N) {
      int j = g - N;
      Bj[j] = -2000.f * r2sq[j] * f;
    } else if (g < 7 * N) {
      Call[g - 2 * N] = 0.f;
    }
  } else if (mode == 1) {
    if (g < N) {
      int p0 = rp1[g], p1 = rp1[g + 1];
      float acc = 0.f;
      for (int p = p0; p < p1; ++p) { float w = vals1[p]; acc = fmaf(w * w, as_[cols1[p]], acc); }
      Ai[g] = -2000.f * (acc - lam * 2048.f * r1sq[g]);
      RLi[g] = -4000.f * lam * rs1[g];
    } else if (g < 2 * N) {
      int j = g - N;
      int p0 = rp2[j], p1 = rp2[j + 1];
      float acc = 0.f;
      for (int p = p0; p < p1; ++p) { float w = vals2[p]; acc = fmaf(w * w, bs_[cols2[p]], acc); }
      Bj[j] = -2000.f * (acc - lam * 2048.f * r2sq[j]);
    } else if (g < 7 * N) {
      Call[g - 2 * N] = 0.f;
    }
  } else {
    if (g < N) {
      int p0 = rp1[g], p1 = rp1[g + 1];
      float acc = 0.f;
      for (int p = p0; p < p1; ++p) { float w = vals1[p]; acc = fmaf(w * w, as_[cols1[p]], acc); }
      Ai[g] = acc;                                      // paf
    } else if (g < 2 * N) {
      int j = g - N;
      int p0 = rp2[j], p1 = rp2[j + 1];
      float acc = 0.f;
      for (int p = p0; p < p1; ++p) { float w = vals2[p]; acc = fmaf(w * w, bs_[cols2[p]], acc); }
      Bj[j] = acc;                                      // pbf
    }
  }
}

// ---------------------------------------------------------------- sinkhorn iteration (streaming)
// Block owns rows r0..r0+3. Phase 0: reconstruct v_{r-1} = vbIn - logN - log(Cprev)
// (MODE 1/2: v_{r-1} = 0); write the 4-col slice of v_{r-1} to vbOut (single writer).
// Phase A: u_r = -logN - LSE_row(K + v_{r-1}); MODE 1/2 build K (+M for MODE 1) and write it.
// Phase B: C_r[j] += sum_r exp(K + u_r + v_{r-1})  (each element <= 1/N -> fp32-safe).
template<int MODE>
__global__ __launch_bounds__(256) void k_sink(
    float* __restrict__ K,
    const float* __restrict__ inter, const float* __restrict__ M,
    const float* __restrict__ Ai, const float* __restrict__ Bj,
    const float* __restrict__ RLi, const float* __restrict__ rs2,
    const float* __restrict__ vbIn, float* __restrict__ vbOut,
    const float* __restrict__ Cprev, float* __restrict__ Cnew,
    float* __restrict__ u) {
  __shared__ __align__(16) float vs[N];
  __shared__ float us4[4];
  const int t = threadIdx.x;
  const int b = blockIdx.x;
  const int r0 = b * 4;
  // phase 0
  if (MODE == 0) {
    for (int q = 0; q < 8; ++q) {
      int j = q * 256 + t;
      vs[j] = vbIn[j] - LOGN - __logf(Cprev[j]);
    }
  }
  __syncthreads();
  if (t < 4) vbOut[r0 + t] = (MODE == 0) ? vs[r0 + t] : 0.f;

  const int w = t >> 6, lane = t & 63;
  // phase A: wave w owns row r0+w
  {
    const int row = r0 + w;
    float m = -INFINITY, ss = 0.f;
    if (MODE != 0) {
      const float ai = Ai[row], rli = RLi[row];
      const float* ir = inter + (size_t)row * N;
      const float* mr = M + (size_t)row * N;
      float* Kr = K + (size_t)row * N;
      #pragma unroll
      for (int q = 0; q < 8; ++q) {
        int j = lane * 4 + q * 256;
        float4 iv = *(const float4*)&ir[j];
        float4 bj = *(const float4*)&Bj[j];
        float4 r2 = *(const float4*)&rs2[j];
        float4 kv;
        kv.x = fmaf(-100.f, iv.x, ai + bj.x + rli * r2.x);
        kv.y = fmaf(-100.f, iv.y, ai + bj.y + rli * r2.y);
        kv.z = fmaf(-100.f, iv.z, ai + bj.z + rli * r2.z);
        kv.w = fmaf(-100.f, iv.w, ai + bj.w + rli * r2.w);
        if (MODE == 1) {
          float4 mv = *(const float4*)&mr[j];
          kv.x = fmaf(0.244140625f, mv.x, kv.x);   // 4000/16384 * (M*2^14)
          kv.y = fmaf(0.244140625f, mv.y, kv.y);
          kv.z = fmaf(0.244140625f, mv.z, kv.z);
          kv.w = fmaf(0.244140625f, mv.w, kv.w);
        }
        *(float4*)&Kr[j] = kv;
        float mx = fmaxf(fmaxf(kv.x, kv.y), fmaxf(kv.z, kv.w));
        float nm = fmaxf(m, mx);
        ss = ss * __expf(m - nm) + __expf(kv.x - nm) + __expf(kv.y - nm)
                                 + __expf(kv.z - nm) + __expf(kv.w - nm);
        m = nm;
      }
    } else {
      const float* Kr = K + (size_t)row * N;
      #pragma unroll
      for (int q = 0; q < 8; ++q) {
        int j = lane * 4 + q * 256;
        float4 kv = *(const float4*)&Kr[j];
        float x0 = kv.x + vs[j], x1 = kv.y + vs[j + 1];
        float x2 = kv.z + vs[j + 2], x3 = kv.w + vs[j + 3];
        float mx = fmaxf(fmaxf(x0, x1), fmaxf(x2, x3));
        float nm = fmaxf(m, mx);
        ss = ss * __expf(m - nm) + __expf(x0 - nm) + __expf(x1 - nm)
                                 + __expf(x2 - nm) + __expf(x3 - nm);
        m = nm;
      }
    }
    for (int off = 32; off; off >>= 1) {
      float mo = __shfl_xor(m, off), so = __shfl_xor(ss, off);
      float nm = fmaxf(m, mo);
      ss = ss * __expf(m - nm) + so * __expf(mo - nm);
      m = nm;
    }
    float uw = -LOGN - (m + __logf(ss));
    if (lane == 0) { us4[w] = uw; u[row] = uw; }
  }
  __syncthreads();
  // phase B: column partial sums over own 4 rows (K rows are L2/cache hot)
  {
    float u0 = us4[0], u1 = us4[1], u2 = us4[2], u3 = us4[3];
    const float* K0 = K + (size_t)r0 * N;
    #pragma unroll 2
    for (int q = 0; q < 8; ++q) {
      int j = q * 256 + t;
      float vj = (MODE == 0) ? vs[j] : 0.f;
      float p = __expf(K0[j] + u0 + vj) + __expf(K0[N + j] + u1 + vj)
              + __expf(K0[2 * N + j] + u2 + vj) + __expf(K0[3 * N + j] + u3 + vj);
      atomicAdd(&Cnew[j], p);
    }
  }
}

// s = exp(K + u + v5); v5 = vbIn - logN - log(C5). rowsums -> as_, col partials -> bsp;
// fp16-scaled s always; fp32 s only when W32 (written to the output buffer).
template<int W32>
__global__ __launch_bounds__(256) void k_swrite(const float* __restrict__ K, const float* __restrict__ u,
                                                const float* __restrict__ vbIn, const float* __restrict__ C5,
                                                float* __restrict__ s32, __half* __restrict__ sh,
                                                float* __restrict__ as_, float* __restrict__ bsp) {
  __shared__ __align__(16) float vs[N];
  __shared__ __align__(16) float bc[N];
  int t = threadIdx.x;
  for (int j = t; j < N; j += 256) vs[j] = vbIn[j] - LOGN - __logf(C5[j]);
  __syncthreads();
  int lane = t & 63, w = t >> 6;
  float4 cacc[8];
  #pragma unroll
  for (int q = 0; q < 8; ++q) cacc[q] = make_float4(0.f, 0.f, 0.f, 0.f);
  int ibase = blockIdx.x * 8 + w * 2;
  for (int rr = 0; rr < 2; ++rr) {
    int i = ibase + rr;
    float ui = u[i];
    const float* Kr = K + (size_t)i * N;
    float rsum = 0.f;
    #pragma unroll
    for (int q = 0; q < 8; ++q) {
      int j = lane * 4 + q * 256;
      float4 kv = *(const float4*)&Kr[j];
      float4 sv;
      sv.x = __expf(kv.x + ui + vs[j]);
      sv.y = __expf(kv.y + ui + vs[j + 1]);
      sv.z = __expf(kv.z + ui + vs[j + 2]);
      sv.w = __expf(kv.w + ui + vs[j + 3]);
      __half2 h0 = __halves2half2(__float2half_rn(sv.x * SSCALE), __float2half_rn(sv.y * SSCALE));
      __half2 h1 = __halves2half2(__float2half_rn(sv.z * SSCALE), __float2half_rn(sv.w * SSCALE));
      uint2 pk; pk.x = *(u32*)&h0; pk.y = *(u32*)&h1;
      *(uint2*)&sh[(size_t)i * N + j] = pk;
      if (W32) *(float4*)&s32[(size_t)i * N + j] = sv;
      rsum += sv.x + sv.y + sv.z + sv.w;
      cacc[q].x += sv.x; cacc[q].y += sv.y; cacc[q].z += sv.z; cacc[q].w += sv.w;
    }
    for (int off = 32; off; off >>= 1) rsum += __shfl_down(rsum, off);
    if (lane == 0) as_[i] = rsum;
  }
  for (int ww = 0; ww < 4; ++ww) {
    if (w == ww) {
      #pragma unroll
      for (int q = 0; q < 8; ++q) {
        int j = lane * 4 + q * 256;
        if (ww == 0) *(float4*)&bc[j] = cacc[q];
        else {
          float4 old = *(float4*)&bc[j];
          old.x += cacc[q].x; old.y += cacc[q].y; old.z += cacc[q].z; old.w += cacc[q].w;
          *(float4*)&bc[j] = old;
        }
      }
    }
    __syncthreads();
  }
  float* bout = bsp + (size_t)blockIdx.x * N;
  for (int j = t * 4; j < N; j += 1024) *(float4*)&bout[j] = *(const float4*)&bc[j];
}

__global__ __launch_bounds__(256) void k_bscomb(const float* __restrict__ bsp, float* __restrict__ bs_) {
  int c = blockIdx.x * 256 + threadIdx.x;
  float acc = 0.f;
  for (int b = 0; b < 256; ++b) acc += bsp[(size_t)b * N + c];
  bs_[c] = acc;
}

// ---------------------------------------------------------------- final

__global__ __launch_bounds__(256) void k_fstats(const float* __restrict__ inter, const float* __restrict__ s,
                                                const float* __restrict__ M, const float* __restrict__ rs2,
                                                float* __restrict__ sisr, float* __restrict__ yv,
                                                double* __restrict__ dotp) {
  __shared__ __align__(16) float r2[N];
  __shared__ double redm[4];
  int t = threadIdx.x;
  for (int j = t * 4; j < N; j += 1024) *(float4*)&r2[j] = *(const float4*)&rs2[j];
  __syncthreads();
  int lane = t & 63, w = t >> 6;
  int i = blockIdx.x * 4 + w;
  const float* ir = inter + (size_t)i * N;
  const float* sr = s + (size_t)i * N;
  const float* mr = M + (size_t)i * N;
  float d1 = 0.f, d2 = 0.f;
  double dm = 0.0;
  for (int j = lane * 4; j < N; j += 256) {
    float4 iv = *(const float4*)&ir[j];
    float4 sv = *(const float4*)&sr[j];
    float4 mv = *(const float4*)&mr[j];
    d1 += iv.x * sv.x + iv.y * sv.y + iv.z * sv.z + iv.w * sv.w;
    d2 += sv.x * r2[j] + sv.y * r2[j + 1] + sv.z * r2[j + 2] + sv.w * r2[j + 3];
    dm += (double)(mv.x * sv.x) + (double)(mv.y * sv.y)
        + (double)(mv.z * sv.z) + (double)(mv.w * sv.w);
  }
  for (int off = 32; off; off >>= 1) {
    d1 += __shfl_down(d1, off);
    d2 += __shfl_down(d2, off);
    dm += __shfl_down(dm, off);
  }
  if (lane == 0) { sisr[i] = d1; yv[i] = d2; redm[w] = dm; }
  __syncthreads();
  if (t == 0) dotp[blockIdx.x] = (redm[0] + redm[1] + redm[2] + redm[3]) * (double)ISCALE;
}

__global__ __launch_bounds__(256) void k_final(
    const float* __restrict__ paf, const float* __restrict__ pbf,
    const float* __restrict__ r1sq, const float* __restrict__ r2sq,
    const float* __restrict__ rs1, const float* __restrict__ rs2,
    const float* __restrict__ as_, const float* __restrict__ bs_,
    const float* __restrict__ yv, const float* __restrict__ sisr,
    const double* __restrict__ k1p, const double* __restrict__ dotp,
    const float* __restrict__ lamp, float* __restrict__ out_loss, float* __restrict__ out_lam) {
  __shared__ double red[256];
  int t = threadIdx.x;
  auto dred = [&](double acc) -> double {
    red[t] = acc; __syncthreads();
    for (int off = 128; off; off >>= 1) { if (t < off) red[t] += red[t + off]; __syncthreads(); }
    double r = red[0]; __syncthreads();
    return r;
  };
  auto dotv = [&](const float* a, const float* b) -> double {
    double acc = 0.0;
    for (int k = t; k < N; k += 256) acc += (double)a[k] * (b ? (double)b[k] : 1.0);
    return dred(acc);
  };
  double k1a = 0.0;
  for (int k = t; k < 1024; k += 256) k1a += k1p[k];
  double k1 = dred(k1a);
  double sma = 0.0;
  for (int k = t; k < 512; k += 256) sma += dotp[k];
  double smfs = dred(sma);
  double paas = dotv(paf, as_);
  double pbbs = dotv(pbf, bs_);
  double r1as = dotv(r1sq, as_);
  double c2bs = dotv(r2sq, bs_);
  double rs1y = dotv(rs1, yv);
  double sis  = dotv(sisr, nullptr);
  double sr1  = dotv(r1sq, nullptr);
  double sr2  = dotv(r2sq, nullptr);
  double ss1  = dotv(rs1, nullptr);
  double ss2  = dotv(rs2, nullptr);
  if (t == 0) {
    double lam0 = (double)*lamp;
    double k2 = 2048.0 * r1as + 2048.0 * c2bs - 2.0 * rs1y;
    double k3 = 2048.0 * 2048.0 * (sr1 + sr2) - 2.0 * ss1 * ss2;
    double upd = (k1 + 40.0 * k2) / (40.0 * k3);
    double lamn = 0.01 * upd + 0.99 * lam0;
    double g1 = paas + pbbs - 2.0 * smfs;
    double wl = sis - lamn * k1;
    double gwl = g1 - 2.0 * lamn * k2 + lamn * lamn * k3;
    double loss = wl + 20.0 * gwl + 20.0;
    *out_loss = (float)loss;
    *out_lam = (float)lamn;
  }
}

// ---------------------------------------------------------------- launch

extern "C" void kernel_launch(void* const* d_in, const int* in_sizes, int n_in,
                              void* d_out, int out_size, void* d_ws, size_t ws_size,
                              hipStream_t stream) {
  (void)in_sizes; (void)n_in; (void)out_size; (void)ws_size;
  const float* out1 = (const float*)d_in[0];
  const float* out2 = (const float*)d_in[1];
  const float* adj1 = (const float*)d_in[2];
  const float* adj2 = (const float*)d_in[3];
  const float* lamp = (const float*)d_in[4];
  float* o = (float*)d_out;
  float* sOut = o + 1;   // fp32 s lives in the output buffer (written at t==9)

  char* w = (char*)d_ws;
  size_t off = 0;
  auto alloc = [&](size_t bytes) -> void* {
    void* p = w + off;
    off = (off + bytes + 255) & ~(size_t)255;
    return p;
  };
  const size_t NNf = (size_t)N * N * sizeof(float);
  float* inter = (float*)alloc(NNf);
  float* Mbuf  = (float*)alloc(NNf);
  float* Kbuf  = (float*)alloc(NNf);
  __half* sh   = (__half*)alloc((size_t)N * N * sizeof(__half));
  __half* Tth  = (__half*)alloc((size_t)N * N * sizeof(__half));
  int* rp1   = (int*)alloc((N + 1) * sizeof(int));
  int* rp2   = (int*)alloc((N + 1) * sizeof(int));
  int* cnt   = (int*)alloc(N * sizeof(int));
  int* cols1 = (int*)alloc(CAP * sizeof(int));
  int* rows1 = (int*)alloc(CAP * sizeof(int));
  int* cols2 = (int*)alloc(CAP * sizeof(int));
  int* rows2 = (int*)alloc(CAP * sizeof(int));
  float* vals1 = (float*)alloc(CAP * sizeof(float));
  float* vals2 = (float*)alloc(CAP * sizeof(float));
  float* r1sq = (float*)alloc(N * sizeof(float));
  float* rs1  = (float*)alloc(N * sizeof(float));
  float* r2sq = (float*)alloc(N * sizeof(float));
  float* rs2v = (float*)alloc(N * sizeof(float));
  float* asv  = (float*)alloc(N * sizeof(float));
  float* bsv  = (float*)alloc(N * sizeof(float));
  float* uv   = (float*)alloc(N * sizeof(float));
  float* vbA  = (float*)alloc(N * sizeof(float));
  float* vbB  = (float*)alloc(N * sizeof(float));
  float* Ai   = (float*)alloc(N * sizeof(float));
  float* Bj   = (float*)alloc(N * sizeof(float));
  float* RLi  = (float*)alloc(N * sizeof(float));
  float* yv   = (float*)alloc(N * sizeof(float));
  float* sisr = (float*)alloc(N * sizeof(float));
  float* Call = (float*)alloc((size_t)5 * N * sizeof(float));
  float* bsp  = (float*)alloc((size_t)256 * N * sizeof(float));
  double* k1p = (double*)alloc(1024 * sizeof(double));
  double* dotp= (double*)alloc(512 * sizeof(double));

  dim3 b(256);

  // ---- precompute
  k_gemm_inter<<<dim3(32, 32), b, 0, stream>>>(out1, out2, inter, k1p);
  k_count<<<512, b, 0, stream>>>(adj1, cnt);
  k_scan<<<1, b, 0, stream>>>(cnt, rp1);
  k_count<<<512, b, 0, stream>>>(adj2, cnt);
  k_scan<<<1, b, 0, stream>>>(cnt, rp2);
  k_fill<<<512, b, 0, stream>>>(adj1, rp1, cols1, rows1);
  k_fill<<<512, b, 0, stream>>>(adj2, rp2, cols2, rows2);
  k_vals<<<2048, b, 0, stream>>>(rp1, rows1, cols1, vals1, out1);
  k_vals<<<2048, b, 0, stream>>>(rp2, rows2, cols2, vals2, out2);
  k_rowstats<<<512, b, 0, stream>>>(rp1, vals1, rs1, r1sq);
  k_rowstats<<<512, b, 0, stream>>>(rp2, vals2, rs2v, r2sq);

  // ---- outer loop
  for (int t = 0; t < 10; ++t) {
    k_prep<<<56, b, 0, stream>>>((t == 0) ? 0 : 1, rp1, cols1, vals1, rp2, cols2, vals2,
                                 r1sq, rs1, r2sq, rs2v, asv, bsv, lamp, Ai, Bj, RLi, Call);
    if (t > 0) {
      k_spmmt<true><<<2048, b, 0, stream>>>(rp1, cols1, vals1, sh, Tth, nullptr);
      k_spmmt<false><<<2048, b, 0, stream>>>(rp2, cols2, vals2, Tth, nullptr, Mbuf);
      k_sink<1><<<512, b, 0, stream>>>(Kbuf, inter, Mbuf, Ai, Bj, RLi, rs2v,
                                       nullptr, vbA, nullptr, Call, uv);
    } else {
      k_sink<2><<<512, b, 0, stream>>>(Kbuf, inter, Mbuf, Ai, Bj, RLi, rs2v,
                                       nullptr, vbA, nullptr, Call, uv);
    }
    // iterations r=2..5: vb ping-pong, C chain
    k_sink<0><<<512, b, 0, stream>>>(Kbuf, inter, Mbuf, Ai, Bj, RLi, rs2v,
                                     vbA, vbB, Call, Call + N, uv);
    k_sink<0><<<512, b, 0, stream>>>(Kbuf, inter, Mbuf, Ai, Bj, RLi, rs2v,
                                     vbB, vbA, Call + N, Call + 2 * N, uv);
    k_sink<0><<<512, b, 0, stream>>>(Kbuf, inter, Mbuf, Ai, Bj, RLi, rs2v,
                                     vbA, vbB, Call + 2 * N, Call + 3 * N, uv);
    k_sink<0><<<512, b, 0, stream>>>(Kbuf, inter, Mbuf, Ai, Bj, RLi, rs2v,
                                     vbB, vbA, Call + 3 * N, Call + 4 * N, uv);
    if (t == 9)
      k_swrite<1><<<256, b, 0, stream>>>(Kbuf, uv, vbA, Call + 4 * N, sOut, sh, asv, bsp);
    else
      k_swrite<0><<<256, b, 0, stream>>>(Kbuf, uv, vbA, Call + 4 * N, nullptr, sh, asv, bsp);
    k_bscomb<<<8, b, 0, stream>>>(bsp, bsv);
  }

  // ---- final: lambda update + loss
  k_spmmt<true><<<2048, b, 0, stream>>>(rp1, cols1, vals1, sh, Tth, nullptr);
  k_spmmt<false><<<2048, b, 0, stream>>>(rp2, cols2, vals2, Tth, nullptr, Mbuf);
  k_prep<<<56, b, 0, stream>>>(2, rp1, cols1, vals1, rp2, cols2, vals2,
                               r1sq, rs1, r2sq, rs2v, asv, bsv, lamp, Ai, Bj, RLi, Call);
  k_fstats<<<512, b, 0, stream>>>(inter, sOut, Mbuf, rs2v, sisr, yv, dotp);
  k_final<<<1, b, 0, stream>>>(Ai, Bj, r1sq, r2sq, rs1, rs2v, asv, bsv, yv, sisr,
                               k1p, dotp, lamp, o, o + 1 + (size_t)N * N);
}

// Round 8
// 1201.143 us; speedup vs baseline: 1.8152x; 1.8152x over previous
//
#include <hip/hip_runtime.h>
#include <math.h>

#define N 2048
#define DIM 128
#define CAP (N*64)
#define LOGN 7.6246189861593985f

typedef unsigned long long u64;
typedef unsigned int u32;
typedef unsigned short u16;

__device__ __forceinline__ u32 bf16bits(float f) {
  u32 x = __float_as_uint(f);
  return (x + 0x7fffu + ((x >> 16) & 1u)) >> 16;
}
__device__ __forceinline__ u32 pack_bf16x2(float lo, float hi) {
  return bf16bits(lo) | (bf16bits(hi) << 16);
}
__device__ __forceinline__ float bflo(u32 u) { return __uint_as_float(u << 16); }
__device__ __forceinline__ float bfhi(u32 u) { return __uint_as_float(u & 0xffff0000u); }

// ---------------------------------------------------------------- precompute

// inter = exp(-(A @ B^T)); per-block partial sums -> k1p
__global__ __launch_bounds__(256) void k_gemm_inter(
    const float* __restrict__ A, const float* __restrict__ B,
    float* __restrict__ O, double* __restrict__ k1p) {
  __shared__ __align__(16) float As[64][65];
  __shared__ __align__(16) float Bs[64][65];
  __shared__ float red[256];
  const int t = threadIdx.x;
  const int i0 = blockIdx.y * 64, j0 = blockIdx.x * 64;
  const int tx = t & 15, ty = t >> 4;
  float acc[4][4] = {};
  for (int kk = 0; kk < DIM; kk += 64) {
    if (kk) __syncthreads();
    for (int q = t; q < 64 * 16; q += 256) {
      int row = q >> 4, k4 = (q & 15) << 2;
      float4 av = *(const float4*)&A[(size_t)(i0 + row) * DIM + kk + k4];
      As[k4 + 0][row] = av.x; As[k4 + 1][row] = av.y;
      As[k4 + 2][row] = av.z; As[k4 + 3][row] = av.w;
      float4 bv = *(const float4*)&B[(size_t)(j0 + row) * DIM + kk + k4];
      Bs[k4 + 0][row] = bv.x; Bs[k4 + 1][row] = bv.y;
      Bs[k4 + 2][row] = bv.z; Bs[k4 + 3][row] = bv.w;
    }
    __syncthreads();
    #pragma unroll 4
    for (int k = 0; k < 64; ++k) {
      float av[4], bv[4];
      #pragma unroll
      for (int d = 0; d < 4; ++d) { av[d] = As[k][ty * 4 + d]; bv[d] = Bs[k][tx * 4 + d]; }
      #pragma unroll
      for (int di = 0; di < 4; ++di)
        #pragma unroll
        for (int dj = 0; dj < 4; ++dj)
          acc[di][dj] = fmaf(av[di], bv[dj], acc[di][dj]);
    }
  }
  float psum = 0.f;
  #pragma unroll
  for (int di = 0; di < 4; ++di)
    #pragma unroll
    for (int dj = 0; dj < 4; ++dj) {
      float vv = __expf(-acc[di][dj]);
      O[(size_t)(i0 + ty * 4 + di) * N + (j0 + tx * 4 + dj)] = vv;
      psum += vv;
    }
  red[t] = psum; __syncthreads();
  for (int off = 128; off; off >>= 1) { if (t < off) red[t] += red[t + off]; __syncthreads(); }
  if (t == 0) k1p[blockIdx.y * 32 + blockIdx.x] = (double)red[0];
}

__global__ __launch_bounds__(256) void k_count(const float* __restrict__ adj, int* __restrict__ cnt) {
  int i = blockIdx.x * 4 + (threadIdx.x >> 6);
  int lane = threadIdx.x & 63;
  const float* row = adj + (size_t)i * N;
  int c = 0;
  for (int j = lane; j < N; j += 64) c += (row[j] != 0.f) ? 1 : 0;
  for (int off = 32; off; off >>= 1) c += __shfl_down(c, off);
  if (lane == 0) cnt[i] = c;
}

__global__ __launch_bounds__(256) void k_scan(const int* __restrict__ cnt, int* __restrict__ rp) {
  __shared__ int sums[256];
  int t = threadIdx.x;
  int local[8]; int run = 0;
  int base = t * 8;
  #pragma unroll
  for (int k = 0; k < 8; ++k) { local[k] = run; run += cnt[base + k]; }
  sums[t] = run; __syncthreads();
  for (int off = 1; off < 256; off <<= 1) {
    int val = (t >= off) ? sums[t - off] : 0;
    __syncthreads();
    sums[t] += val;
    __syncthreads();
  }
  int pre = (t == 0) ? 0 : sums[t - 1];
  #pragma unroll
  for (int k = 0; k < 8; ++k) rp[base + k] = pre + local[k];
  if (t == 255) rp[N] = sums[255];
}

__global__ __launch_bounds__(256) void k_fill(const float* __restrict__ adj, const int* __restrict__ rp,
                                              int* __restrict__ cols, int* __restrict__ rows) {
  int i = blockIdx.x * 4 + (threadIdx.x >> 6);
  int lane = threadIdx.x & 63;
  const float* row = adj + (size_t)i * N;
  int pos = rp[i];
  for (int j0 = 0; j0 < N; j0 += 64) {
    bool p = row[j0 + lane] != 0.f;
    u64 mask = __ballot(p);
    if (p) {
      int off = __popcll(mask & ((1ull << lane) - 1ull));
      cols[pos + off] = j0 + lane;
      rows[pos + off] = i;
    }
    pos += __popcll(mask);
  }
}

__global__ __launch_bounds__(256) void k_vals(const int* __restrict__ rp, const int* __restrict__ rows,
                                              const int* __restrict__ cols, float* __restrict__ vals,
                                              const float* __restrict__ emb) {
  int lane = threadIdx.x & 63;
  int total = rp[N];
  for (int p = blockIdx.x * 4 + (threadIdx.x >> 6); p < total; p += 8192) {
    int i = rows[p], k = cols[p];
    const float* ei = emb + (size_t)i * DIM;
    const float* ek = emb + (size_t)k * DIM;
    float s = ei[lane] * ek[lane] + ei[lane + 64] * ek[lane + 64];
    for (int off = 32; off; off >>= 1) s += __shfl_down(s, off);
    if (lane == 0) vals[p] = __expf(-s);
  }
}

__global__ __launch_bounds__(256) void k_rowstats(const int* __restrict__ rp, const float* __restrict__ vals,
                                                  float* __restrict__ rs, float* __restrict__ rsq) {
  int i = blockIdx.x * 4 + (threadIdx.x >> 6);
  int lane = threadIdx.x & 63;
  int p0 = rp[i], p1 = rp[i + 1];
  float s1 = 0.f, s2 = 0.f;
  for (int p = p0 + lane; p < p1; p += 64) { float w = vals[p]; s1 += w; s2 += w * w; }
  for (int off = 32; off; off >>= 1) { s1 += __shfl_down(s1, off); s2 += __shfl_down(s2, off); }
  if (lane == 0) { rs[i] = s1; rsq[i] = s2; }
}

// ---------------------------------------------------------------- spmm (bf16 gather)
// V=0: S = P bf16; weights folded with a[col]; output *= b[c]; bf16 out (Tt).
// V=1: S = Tt bf16; plain weights; fp32 out (M row-major via double transpose).
template<int V>
__global__ __launch_bounds__(256) void k_spmmt(const int* __restrict__ rp, const int* __restrict__ cols,
                                               const float* __restrict__ vals, const u16* __restrict__ S,
                                               const float* __restrict__ af, const float* __restrict__ bf,
                                               u16* __restrict__ OutB, float* __restrict__ OutF) {
  __shared__ int winc[1024];
  __shared__ float winv[1024];
  __shared__ int rb[9];
  const int t = threadIdx.x;
  const int tile = blockIdx.x & 7;
  const int c = tile * 256 + t;
  const int i0 = (blockIdx.x >> 3) * 8;
  const int p0 = rp[i0];
  if (t < 9) rb[t] = rp[i0 + t] - p0;
  __syncthreads();
  const int nn = rb[8];
  for (int k = t; k < nn; k += 256) {
    int col = cols[p0 + k];
    winc[k] = col << 11;
    winv[k] = (V == 0) ? vals[p0 + k] * af[col] : vals[p0 + k];
  }
  __syncthreads();
  float a[8];
  #pragma unroll
  for (int r = 0; r < 8; ++r) {
    int pe = rb[r + 1];
    int p = rb[r];
    float a0 = 0.f, a1 = 0.f, a2 = 0.f, a3 = 0.f;
    for (; p + 3 < pe; p += 4) {
      a0 = fmaf(winv[p],     __uint_as_float((u32)S[winc[p]     + c] << 16), a0);
      a1 = fmaf(winv[p + 1], __uint_as_float((u32)S[winc[p + 1] + c] << 16), a1);
      a2 = fmaf(winv[p + 2], __uint_as_float((u32)S[winc[p + 2] + c] << 16), a2);
      a3 = fmaf(winv[p + 3], __uint_as_float((u32)S[winc[p + 3] + c] << 16), a3);
    }
    for (; p < pe; ++p) a0 = fmaf(winv[p], __uint_as_float((u32)S[winc[p] + c] << 16), a0);
    a[r] = (a0 + a1) + (a2 + a3);
  }
  size_t ob = (size_t)(tile * 256 + t) * N + i0;
  if (V == 0) {
    float bc = bf[c];
    #pragma unroll
    for (int r = 0; r < 8; ++r) a[r] *= bc;
    uint4 pk;
    pk.x = pack_bf16x2(a[0], a[1]); pk.y = pack_bf16x2(a[2], a[3]);
    pk.z = pack_bf16x2(a[4], a[5]); pk.w = pack_bf16x2(a[6], a[7]);
    *(uint4*)&OutB[ob] = pk;
  } else {
    *(float4*)&OutF[ob]     = make_float4(a[0], a[1], a[2], a[3]);
    *(float4*)&OutF[ob + 4] = make_float4(a[4], a[5], a[6], a[7]);
  }
}

// ---------------------------------------------------------------- prep
// mode 0: t==0 analytic; mode 1: general (bs == 1/N exact); mode 2: final paf/pbf
__global__ __launch_bounds__(256) void k_prep(
    int mode,
    const int* __restrict__ rp1, const int* __restrict__ cols1, const float* __restrict__ vals1,
    const float* __restrict__ r1sq, const float* __restrict__ rs1,
    const float* __restrict__ r2sq, const float* __restrict__ lamp,
    const float* __restrict__ as_,
    float* __restrict__ Ai, float* __restrict__ Bj, float* __restrict__ RLi) {
  int g = blockIdx.x * 256 + threadIdx.x;
  float lam = *lamp;
  float f = 0.00048828125f - lam * 2048.f;   // 1/2048 - 2048*lam
  if (mode == 0) {
    if (g < N) {
      Ai[g] = -2000.f * r1sq[g] * f;
      RLi[g] = 4000.f * rs1[g] * (2.384185791015625e-07f - lam);
    } else {
      int j = g - N;
      Bj[j] = -2000.f * r2sq[j] * f;
    }
  } else if (mode == 1) {
    if (g < N) {
      int p0 = rp1[g], p1 = rp1[g + 1];
      float acc = 0.f;
      for (int p = p0; p < p1; ++p) { float w = vals1[p]; acc = fmaf(w * w, as_[cols1[p]], acc); }
      Ai[g] = -2000.f * (acc - lam * 2048.f * r1sq[g]);
      RLi[g] = -4000.f * lam * rs1[g];
    } else {
      int j = g - N;
      Bj[j] = -2000.f * r2sq[j] * f;
    }
  } else {
    if (g < N) {
      int p0 = rp1[g], p1 = rp1[g + 1];
      float acc = 0.f;
      for (int p = p0; p < p1; ++p) { float w = vals1[p]; acc = fmaf(w * w, as_[cols1[p]], acc); }
      Ai[g] = acc;                                       // paf
    } else {
      int j = g - N;
      Bj[j] = r2sq[j] * 0.00048828125f;                  // pbf = r2sq/N (bs = 1/N exact)
    }
  }
}

// ---------------------------------------------------------------- exp-domain sinkhorn iteration
// Block owns rows r0..r0+3 of P (bf16, LDS-staged). MODE 2: build P=exp(K-mu) w/o M (t==0);
// MODE 1: build with M; MODE 0: plain iteration (reads P, b).
// Row phase: a_i = 1/(N * sum_j P_ij b_j)  (build: b=1, sum = ss).
// Col phase: part[b][j] = sum_{4 rows} P_ij a_i  (linear, no atomics).
template<int MODE>
__global__ __launch_bounds__(256) void k_iter(
    u32* __restrict__ P,
    const float* __restrict__ inter, const float* __restrict__ M,
    const float* __restrict__ Ai, const float* __restrict__ Bj,
    const float* __restrict__ RLi, const float* __restrict__ rs2,
    const float* __restrict__ bvec, float* __restrict__ avec,
    float* __restrict__ part) {
  __shared__ u32 Pl[4 * 1024];       // 16 KB: 4 rows x 2048 bf16
  __shared__ float bl[N];            // 8 KB
  __shared__ float a4[4];
  const int t = threadIdx.x;
  const int r0 = blockIdx.x * 4;
  const int w = t >> 6, lane = t & 63;
  const int row = r0 + w;

  if (MODE == 0) {
    #pragma unroll
    for (int q = 0; q < 2; ++q) {
      int j = (q * 256 + t) * 4;
      *(float4*)&bl[j] = *(const float4*)&bvec[j];
    }
    #pragma unroll
    for (int q = 0; q < 4; ++q) {
      int g = (q * 256 + t) * 4;
      *(uint4*)&Pl[g] = *(const uint4*)&P[(size_t)r0 * 1024 + g];
    }
    __syncthreads();
    float y = 0.f;
    const u32* Pr = Pl + w * 1024;
    #pragma unroll
    for (int k = 0; k < 16; ++k) {
      int g = lane + k * 64;
      u32 u = Pr[g];
      y = fmaf(bflo(u), bl[2 * g], y);
      y = fmaf(bfhi(u), bl[2 * g + 1], y);
    }
    for (int off = 32; off; off >>= 1) y += __shfl_xor(y, off);
    if (lane == 0) { float aw = 1.f / (2048.f * y); a4[w] = aw; avec[row] = aw; }
  } else {
    float kv[32];
    float m = -INFINITY;
    const float ai_ = Ai[row], rli = RLi[row];
    const float* ir = inter + (size_t)row * N;
    const float* mr = M + (size_t)row * N;
    #pragma unroll
    for (int q = 0; q < 8; ++q) {
      int j = lane * 4 + q * 256;
      float4 iv = *(const float4*)&ir[j];
      float4 bj = *(const float4*)&Bj[j];
      float4 r2 = *(const float4*)&rs2[j];
      float k0 = fmaf(-100.f, iv.x, ai_ + bj.x + rli * r2.x);
      float k1 = fmaf(-100.f, iv.y, ai_ + bj.y + rli * r2.y);
      float k2 = fmaf(-100.f, iv.z, ai_ + bj.z + rli * r2.z);
      float k3 = fmaf(-100.f, iv.w, ai_ + bj.w + rli * r2.w);
      if (MODE == 1) {
        float4 mv = *(const float4*)&mr[j];
        k0 = fmaf(4000.f, mv.x, k0);
        k1 = fmaf(4000.f, mv.y, k1);
        k2 = fmaf(4000.f, mv.z, k2);
        k3 = fmaf(4000.f, mv.w, k3);
      }
      kv[q * 4 + 0] = k0; kv[q * 4 + 1] = k1; kv[q * 4 + 2] = k2; kv[q * 4 + 3] = k3;
      m = fmaxf(m, fmaxf(fmaxf(k0, k1), fmaxf(k2, k3)));
    }
    for (int off = 32; off; off >>= 1) m = fmaxf(m, __shfl_xor(m, off));
    float ss = 0.f;
    #pragma unroll
    for (int q = 0; q < 8; ++q) {
      float p0 = __expf(kv[q * 4 + 0] - m);
      float p1 = __expf(kv[q * 4 + 1] - m);
      float p2 = __expf(kv[q * 4 + 2] - m);
      float p3 = __expf(kv[q * 4 + 3] - m);
      ss += (p0 + p1) + (p2 + p3);
      u32 lo = pack_bf16x2(p0, p1), hi = pack_bf16x2(p2, p3);
      int g = lane * 2 + q * 128;
      Pl[w * 1024 + g] = lo; Pl[w * 1024 + g + 1] = hi;
      *(uint2*)&P[(size_t)row * 1024 + g] = make_uint2(lo, hi);
    }
    for (int off = 32; off; off >>= 1) ss += __shfl_xor(ss, off);
    if (lane == 0) { float aw = 1.f / (2048.f * ss); a4[w] = aw; avec[row] = aw; }
  }
  __syncthreads();
  const float a0 = a4[0], a1 = a4[1], a2 = a4[2], a3 = a4[3];
  #pragma unroll
  for (int k = 0; k < 4; ++k) {
    int g = k * 256 + t;
    u32 u0 = Pl[g], u1 = Pl[1024 + g], u2 = Pl[2048 + g], u3 = Pl[3072 + g];
    float zlo = bflo(u0) * a0 + bflo(u1) * a1 + bflo(u2) * a2 + bflo(u3) * a3;
    float zhi = bfhi(u0) * a0 + bfhi(u1) * a1 + bfhi(u2) * a2 + bfhi(u3) * a3;
    *(float2*)&part[(size_t)blockIdx.x * N + 2 * g] = make_float2(zlo, zhi);
  }
}

// combine 512 partials -> b = 1/(N*z). 128 blocks x 16 cols.
__global__ __launch_bounds__(256) void k_comb(const float* __restrict__ part, float* __restrict__ bvec) {
  __shared__ float pp[16][17];
  const int t = threadIdx.x;
  const int cl = t & 15, kg = t >> 4;
  const int c = blockIdx.x * 16 + cl;
  float z = 0.f;
  for (int k = kg * 32; k < kg * 32 + 32; ++k) z += part[(size_t)k * N + c];
  pp[kg][cl] = z;
  __syncthreads();
  if (t < 16) {
    float zz = 0.f;
    #pragma unroll
    for (int g = 0; g < 16; ++g) zz += pp[g][t];
    bvec[blockIdx.x * 16 + t] = 1.f / (2048.f * zz);
  }
}

// as_[i] = a_i * sum_j P_ij b_j  (final b of this outer iteration)
__global__ __launch_bounds__(256) void k_rowfin(const u32* __restrict__ P, const float* __restrict__ bvec,
                                                const float* __restrict__ avec, float* __restrict__ as_) {
  __shared__ float bl[N];
  const int t = threadIdx.x;
  #pragma unroll
  for (int q = 0; q < 2; ++q) {
    int j = (q * 256 + t) * 4;
    *(float4*)&bl[j] = *(const float4*)&bvec[j];
  }
  __syncthreads();
  const int w = t >> 6, lane = t & 63;
  const int row = blockIdx.x * 4 + w;
  const u32* Pr = P + (size_t)row * 1024;
  float y = 0.f;
  #pragma unroll
  for (int k = 0; k < 16; ++k) {
    int g = lane + k * 64;
    u32 u = Pr[g];
    y = fmaf(bflo(u), bl[2 * g], y);
    y = fmaf(bfhi(u), bl[2 * g + 1], y);
  }
  for (int off = 32; off; off >>= 1) y += __shfl_xor(y, off);
  if (lane == 0) as_[row] = avec[row] * y;
}

// ---------------------------------------------------------------- final
// s = a*P*b on the fly; writes s to output; sisr/yv row stats; dotp = partial of sum(M.*s)
__global__ __launch_bounds__(256) void k_fstats(
    const float* __restrict__ inter, const u32* __restrict__ P, const float* __restrict__ M,
    const float* __restrict__ rs2, const float* __restrict__ avec, const float* __restrict__ bvec,
    float* __restrict__ sOut, float* __restrict__ sisr, float* __restrict__ yv,
    double* __restrict__ dotp) {
  __shared__ __align__(16) float r2[N];
  __shared__ __align__(16) float bl[N];
  __shared__ double redm[4];
  const int t = threadIdx.x;
  #pragma unroll
  for (int q = 0; q < 2; ++q) {
    int j = (q * 256 + t) * 4;
    *(float4*)&r2[j] = *(const float4*)&rs2[j];
    *(float4*)&bl[j] = *(const float4*)&bvec[j];
  }
  __syncthreads();
  const int w = t >> 6, lane = t & 63;
  const int row = blockIdx.x * 4 + w;
  const float av = avec[row];
  const float* ir = inter + (size_t)row * N;
  const float* mr = M + (size_t)row * N;
  const u32* Pr = P + (size_t)row * 1024;
  float* sr = sOut + (size_t)row * N;
  float d1 = 0.f, d2 = 0.f;
  double dm = 0.0;
  #pragma unroll 4
  for (int k = 0; k < 16; ++k) {
    int g = lane + k * 64;
    int j = 2 * g;
    u32 u = Pr[g];
    float s0 = bflo(u) * av * bl[j];
    float s1 = bfhi(u) * av * bl[j + 1];
    float2 iv = *(const float2*)&ir[j];
    float2 mv = *(const float2*)&mr[j];
    sr[j] = s0; sr[j + 1] = s1;
    d1 += iv.x * s0 + iv.y * s1;
    d2 += s0 * r2[j] + s1 * r2[j + 1];
    dm += (double)(mv.x * s0) + (double)(mv.y * s1);
  }
  for (int off = 32; off; off >>= 1) {
    d1 += __shfl_down(d1, off);
    d2 += __shfl_down(d2, off);
    dm += __shfl_down(dm, off);
  }
  if (lane == 0) { sisr[row] = d1; yv[row] = d2; redm[w] = dm; }
  __syncthreads();
  if (t == 0) dotp[blockIdx.x] = redm[0] + redm[1] + redm[2] + redm[3];
}

__global__ __launch_bounds__(256) void k_final(
    const float* __restrict__ paf, const float* __restrict__ pbf,
    const float* __restrict__ r1sq, const float* __restrict__ r2sq,
    const float* __restrict__ rs1, const float* __restrict__ rs2,
    const float* __restrict__ as_,
    const float* __restrict__ yv, const float* __restrict__ sisr,
    const double* __restrict__ k1p, const double* __restrict__ dotp,
    const float* __restrict__ lamp, float* __restrict__ out_loss, float* __restrict__ out_lam) {
  __shared__ double red[256];
  int t = threadIdx.x;
  auto dred = [&](double acc) -> double {
    red[t] = acc; __syncthreads();
    for (int off = 128; off; off >>= 1) { if (t < off) red[t] += red[t + off]; __syncthreads(); }
    double r = red[0]; __syncthreads();
    return r;
  };
  auto dotv = [&](const float* a, const float* b) -> double {
    double acc = 0.0;
    for (int k = t; k < N; k += 256) acc += (double)a[k] * (b ? (double)b[k] : 1.0);
    return dred(acc);
  };
  double k1a = 0.0;
  for (int k = t; k < 1024; k += 256) k1a += k1p[k];
  double k1 = dred(k1a);
  double sma = 0.0;
  for (int k = t; k < 512; k += 256) sma += dotp[k];
  double smfs = dred(sma);
  double paas = dotv(paf, as_);
  double pbbs = dotv(pbf, nullptr) * (1.0 / 2048.0);
  double r1as = dotv(r1sq, as_);
  double rs1y = dotv(rs1, yv);
  double sis  = dotv(sisr, nullptr);
  double sr1  = dotv(r1sq, nullptr);
  double sr2  = dotv(r2sq, nullptr);
  double ss1  = dotv(rs1, nullptr);
  double ss2  = dotv(rs2, nullptr);
  if (t == 0) {
    double c2bs = sr2 / 2048.0;
    double lam0 = (double)*lamp;
    double k2 = 2048.0 * r1as + 2048.0 * c2bs - 2.0 * rs1y;
    double k3 = 2048.0 * 2048.0 * (sr1 + sr2) - 2.0 * ss1 * ss2;
    double upd = (k1 + 40.0 * k2) / (40.0 * k3);
    double lamn = 0.01 * upd + 0.99 * lam0;
    double g1 = paas + pbbs - 2.0 * smfs;
    double wl = sis - lamn * k1;
    double gwl = g1 - 2.0 * lamn * k2 + lamn * lamn * k3;
    double loss = wl + 20.0 * gwl + 20.0;
    *out_loss = (float)loss;
    *out_lam = (float)lamn;
  }
}

// ---------------------------------------------------------------- launch

extern "C" void kernel_launch(void* const* d_in, const int* in_sizes, int n_in,
                              void* d_out, int out_size, void* d_ws, size_t ws_size,
                              hipStream_t stream) {
  (void)in_sizes; (void)n_in; (void)out_size; (void)ws_size;
  const float* out1 = (const float*)d_in[0];
  const float* out2 = (const float*)d_in[1];
  const float* adj1 = (const float*)d_in[2];
  const float* adj2 = (const float*)d_in[3];
  const float* lamp = (const float*)d_in[4];
  float* o = (float*)d_out;
  float* sOut = o + 1;

  char* w = (char*)d_ws;
  size_t off = 0;
  auto alloc = [&](size_t bytes) -> void* {
    void* p = w + off;
    off = (off + bytes + 255) & ~(size_t)255;
    return p;
  };
  const size_t NNf = (size_t)N * N * sizeof(float);
  float* inter = (float*)alloc(NNf);
  float* Mbuf  = (float*)alloc(NNf);
  u32*  Pbuf   = (u32*)alloc((size_t)N * 1024 * sizeof(u32));   // bf16 x2 packed
  u16*  Tth    = (u16*)alloc((size_t)N * N * sizeof(u16));      // bf16
  int* rp1   = (int*)alloc((N + 1) * sizeof(int));
  int* rp2   = (int*)alloc((N + 1) * sizeof(int));
  int* cnt   = (int*)alloc(N * sizeof(int));
  int* cols1 = (int*)alloc(CAP * sizeof(int));
  int* rows1 = (int*)alloc(CAP * sizeof(int));
  int* cols2 = (int*)alloc(CAP * sizeof(int));
  int* rows2 = (int*)alloc(CAP * sizeof(int));
  float* vals1 = (float*)alloc(CAP * sizeof(float));
  float* vals2 = (float*)alloc(CAP * sizeof(float));
  float* r1sq = (float*)alloc(N * sizeof(float));
  float* rs1  = (float*)alloc(N * sizeof(float));
  float* r2sq = (float*)alloc(N * sizeof(float));
  float* rs2v = (float*)alloc(N * sizeof(float));
  float* asv  = (float*)alloc(N * sizeof(float));
  float* avec = (float*)alloc(N * sizeof(float));
  float* bvec = (float*)alloc(N * sizeof(float));
  float* Ai   = (float*)alloc(N * sizeof(float));
  float* Bj   = (float*)alloc(N * sizeof(float));
  float* RLi  = (float*)alloc(N * sizeof(float));
  float* yv   = (float*)alloc(N * sizeof(float));
  float* sisr = (float*)alloc(N * sizeof(float));
  float* part = (float*)alloc((size_t)512 * N * sizeof(float));
  double* k1p = (double*)alloc(1024 * sizeof(double));
  double* dotp= (double*)alloc(512 * sizeof(double));

  dim3 b(256);

  // ---- precompute
  k_gemm_inter<<<dim3(32, 32), b, 0, stream>>>(out1, out2, inter, k1p);
  k_count<<<512, b, 0, stream>>>(adj1, cnt);
  k_scan<<<1, b, 0, stream>>>(cnt, rp1);
  k_count<<<512, b, 0, stream>>>(adj2, cnt);
  k_scan<<<1, b, 0, stream>>>(cnt, rp2);
  k_fill<<<512, b, 0, stream>>>(adj1, rp1, cols1, rows1);
  k_fill<<<512, b, 0, stream>>>(adj2, rp2, cols2, rows2);
  k_vals<<<2048, b, 0, stream>>>(rp1, rows1, cols1, vals1, out1);
  k_vals<<<2048, b, 0, stream>>>(rp2, rows2, cols2, vals2, out2);
  k_rowstats<<<512, b, 0, stream>>>(rp1, vals1, rs1, r1sq);
  k_rowstats<<<512, b, 0, stream>>>(rp2, vals2, rs2v, r2sq);

  // ---- outer loop
  for (int t = 0; t < 10; ++t) {
    k_prep<<<16, b, 0, stream>>>((t == 0) ? 0 : 1, rp1, cols1, vals1,
                                 r1sq, rs1, r2sq, lamp, asv, Ai, Bj, RLi);
    if (t > 0) {
      k_spmmt<0><<<2048, b, 0, stream>>>(rp1, cols1, vals1, (const u16*)Pbuf, avec, bvec, Tth, nullptr);
      k_spmmt<1><<<2048, b, 0, stream>>>(rp2, cols2, vals2, Tth, nullptr, nullptr, nullptr, Mbuf);
      k_iter<1><<<512, b, 0, stream>>>(Pbuf, inter, Mbuf, Ai, Bj, RLi, rs2v, bvec, avec, part);
    } else {
      k_iter<2><<<512, b, 0, stream>>>(Pbuf, inter, Mbuf, Ai, Bj, RLi, rs2v, bvec, avec, part);
    }
    k_comb<<<128, b, 0, stream>>>(part, bvec);
    for (int r = 1; r < 5; ++r) {
      k_iter<0><<<512, b, 0, stream>>>(Pbuf, inter, Mbuf, Ai, Bj, RLi, rs2v, bvec, avec, part);
      k_comb<<<128, b, 0, stream>>>(part, bvec);
    }
    k_rowfin<<<512, b, 0, stream>>>(Pbuf, bvec, avec, asv);
  }

  // ---- final: lambda update + loss
  k_spmmt<0><<<2048, b, 0, stream>>>(rp1, cols1, vals1, (const u16*)Pbuf, avec, bvec, Tth, nullptr);
  k_spmmt<1><<<2048, b, 0, stream>>>(rp2, cols2, vals2, Tth, nullptr, nullptr, nullptr, Mbuf);
  k_prep<<<16, b, 0, stream>>>(2, rp1, cols1, vals1,
                               r1sq, rs1, r2sq, lamp, asv, Ai, Bj, RLi);
  k_fstats<<<512, b, 0, stream>>>(inter, Pbuf, Mbuf, rs2v, avec, bvec, sOut, sisr, yv, dotp);
  k_final<<<1, b, 0, stream>>>(Ai, Bj, r1sq, r2sq, rs1, rs2v, asv, yv, sisr,
                               k1p, dotp, lamp, o, o + 1 + (size_t)N * N);
}

// Round 9
// 1037.190 us; speedup vs baseline: 2.1021x; 1.1581x over previous
//
#include <hip/hip_runtime.h>
#include <math.h>

#define N 2048
#define DIM 128
#define CAP (N*64)
#define LOGN 7.6246189861593985f

typedef unsigned long long u64;
typedef unsigned int u32;
typedef unsigned short u16;

__device__ __forceinline__ u32 bf16bits(float f) {
  u32 x = __float_as_uint(f);
  return (x + 0x7fffu + ((x >> 16) & 1u)) >> 16;
}
__device__ __forceinline__ u32 pack_bf16x2(float lo, float hi) {
  return bf16bits(lo) | (bf16bits(hi) << 16);
}
__device__ __forceinline__ float bflo(u32 u) { return __uint_as_float(u << 16); }
__device__ __forceinline__ float bfhi(u32 u) { return __uint_as_float(u & 0xffff0000u); }

// ---------------------------------------------------------------- precompute

__global__ __launch_bounds__(256) void k_gemm_inter(
    const float* __restrict__ A, const float* __restrict__ B,
    float* __restrict__ O, double* __restrict__ k1p) {
  __shared__ __align__(16) float As[64][65];
  __shared__ __align__(16) float Bs[64][65];
  __shared__ float red[256];
  const int t = threadIdx.x;
  const int i0 = blockIdx.y * 64, j0 = blockIdx.x * 64;
  const int tx = t & 15, ty = t >> 4;
  float acc[4][4] = {};
  for (int kk = 0; kk < DIM; kk += 64) {
    if (kk) __syncthreads();
    for (int q = t; q < 64 * 16; q += 256) {
      int row = q >> 4, k4 = (q & 15) << 2;
      float4 av = *(const float4*)&A[(size_t)(i0 + row) * DIM + kk + k4];
      As[k4 + 0][row] = av.x; As[k4 + 1][row] = av.y;
      As[k4 + 2][row] = av.z; As[k4 + 3][row] = av.w;
      float4 bv = *(const float4*)&B[(size_t)(j0 + row) * DIM + kk + k4];
      Bs[k4 + 0][row] = bv.x; Bs[k4 + 1][row] = bv.y;
      Bs[k4 + 2][row] = bv.z; Bs[k4 + 3][row] = bv.w;
    }
    __syncthreads();
    #pragma unroll 4
    for (int k = 0; k < 64; ++k) {
      float av[4], bv[4];
      #pragma unroll
      for (int d = 0; d < 4; ++d) { av[d] = As[k][ty * 4 + d]; bv[d] = Bs[k][tx * 4 + d]; }
      #pragma unroll
      for (int di = 0; di < 4; ++di)
        #pragma unroll
        for (int dj = 0; dj < 4; ++dj)
          acc[di][dj] = fmaf(av[di], bv[dj], acc[di][dj]);
    }
  }
  float psum = 0.f;
  #pragma unroll
  for (int di = 0; di < 4; ++di)
    #pragma unroll
    for (int dj = 0; dj < 4; ++dj) {
      float vv = __expf(-acc[di][dj]);
      O[(size_t)(i0 + ty * 4 + di) * N + (j0 + tx * 4 + dj)] = vv;
      psum += vv;
    }
  red[t] = psum; __syncthreads();
  for (int off = 128; off; off >>= 1) { if (t < off) red[t] += red[t + off]; __syncthreads(); }
  if (t == 0) k1p[blockIdx.y * 32 + blockIdx.x] = (double)red[0];
}

__global__ __launch_bounds__(256) void k_count(const float* __restrict__ adj, int* __restrict__ cnt) {
  int i = blockIdx.x * 4 + (threadIdx.x >> 6);
  int lane = threadIdx.x & 63;
  const float* row = adj + (size_t)i * N;
  int c = 0;
  for (int j = lane; j < N; j += 64) c += (row[j] != 0.f) ? 1 : 0;
  for (int off = 32; off; off >>= 1) c += __shfl_down(c, off);
  if (lane == 0) cnt[i] = c;
}

__global__ __launch_bounds__(256) void k_scan(const int* __restrict__ cnt, int* __restrict__ rp) {
  __shared__ int sums[256];
  int t = threadIdx.x;
  int local[8]; int run = 0;
  int base = t * 8;
  #pragma unroll
  for (int k = 0; k < 8; ++k) { local[k] = run; run += cnt[base + k]; }
  sums[t] = run; __syncthreads();
  for (int off = 1; off < 256; off <<= 1) {
    int val = (t >= off) ? sums[t - off] : 0;
    __syncthreads();
    sums[t] += val;
    __syncthreads();
  }
  int pre = (t == 0) ? 0 : sums[t - 1];
  #pragma unroll
  for (int k = 0; k < 8; ++k) rp[base + k] = pre + local[k];
  if (t == 255) rp[N] = sums[255];
}

__global__ __launch_bounds__(256) void k_fill(const float* __restrict__ adj, const int* __restrict__ rp,
                                              int* __restrict__ cols, int* __restrict__ rows) {
  int i = blockIdx.x * 4 + (threadIdx.x >> 6);
  int lane = threadIdx.x & 63;
  const float* row = adj + (size_t)i * N;
  int pos = rp[i];
  for (int j0 = 0; j0 < N; j0 += 64) {
    bool p = row[j0 + lane] != 0.f;
    u64 mask = __ballot(p);
    if (p) {
      int off = __popcll(mask & ((1ull << lane) - 1ull));
      cols[pos + off] = j0 + lane;
      rows[pos + off] = i;
    }
    pos += __popcll(mask);
  }
}

__global__ __launch_bounds__(256) void k_vals(const int* __restrict__ rp, const int* __restrict__ rows,
                                              const int* __restrict__ cols, float* __restrict__ vals,
                                              const float* __restrict__ emb) {
  int lane = threadIdx.x & 63;
  int total = rp[N];
  for (int p = blockIdx.x * 4 + (threadIdx.x >> 6); p < total; p += 8192) {
    int i = rows[p], k = cols[p];
    const float* ei = emb + (size_t)i * DIM;
    const float* ek = emb + (size_t)k * DIM;
    float s = ei[lane] * ek[lane] + ei[lane + 64] * ek[lane + 64];
    for (int off = 32; off; off >>= 1) s += __shfl_down(s, off);
    if (lane == 0) vals[p] = __expf(-s);
  }
}

__global__ __launch_bounds__(256) void k_rowstats(const int* __restrict__ rp, const float* __restrict__ vals,
                                                  float* __restrict__ rs, float* __restrict__ rsq) {
  int i = blockIdx.x * 4 + (threadIdx.x >> 6);
  int lane = threadIdx.x & 63;
  int p0 = rp[i], p1 = rp[i + 1];
  float s1 = 0.f, s2 = 0.f;
  for (int p = p0 + lane; p < p1; p += 64) { float w = vals[p]; s1 += w; s2 += w * w; }
  for (int off = 32; off; off >>= 1) { s1 += __shfl_down(s1, off); s2 += __shfl_down(s2, off); }
  if (lane == 0) { rs[i] = s1; rsq[i] = s2; }
}

// ---------------------------------------------------------------- spmm (bf16 u32-pair gather)
// V=0: S = P; weights folded with af[col]; output cols scaled by bf; Out = Tt (bf16).
// V=1: S = Tt; plain weights; Out = M row-major (bf16).
// Thread owns a u32 col-pair. 4 col-tiles (512 u16 cols) x 512 4-row windows.
template<int V>
__global__ __launch_bounds__(256) void k_spmmt(const int* __restrict__ rp, const int* __restrict__ cols,
                                               const float* __restrict__ vals, const u32* __restrict__ S,
                                               const float* __restrict__ af, const float* __restrict__ bf,
                                               u16* __restrict__ Out) {
  __shared__ int winc[512];
  __shared__ float winv[512];
  __shared__ int rb[5];
  const int t = threadIdx.x;
  const int tile = blockIdx.x & 3;
  const int cu = tile * 256 + t;            // u32 col index (2 u16 cols)
  const int i0 = (blockIdx.x >> 2) * 4;
  const int p0 = rp[i0];
  if (t < 5) rb[t] = rp[i0 + t] - p0;
  __syncthreads();
  const int nn = rb[4];
  for (int k = t; k < nn; k += 256) {
    int col = cols[p0 + k];
    winc[k] = col << 10;                    // * 1024 u32 row stride
    winv[k] = (V == 0) ? vals[p0 + k] * af[col] : vals[p0 + k];
  }
  __syncthreads();
  float alo[4], ahi[4];
  #pragma unroll
  for (int r = 0; r < 4; ++r) {
    int pe = rb[r + 1], p = rb[r];
    float l0 = 0.f, l1 = 0.f, h0 = 0.f, h1 = 0.f;
    for (; p + 1 < pe; p += 2) {
      u32 u0 = S[winc[p] + cu], u1 = S[winc[p + 1] + cu];
      l0 = fmaf(winv[p],     bflo(u0), l0);  h0 = fmaf(winv[p],     bfhi(u0), h0);
      l1 = fmaf(winv[p + 1], bflo(u1), l1);  h1 = fmaf(winv[p + 1], bfhi(u1), h1);
    }
    if (p < pe) {
      u32 u = S[winc[p] + cu];
      l0 = fmaf(winv[p], bflo(u), l0);  h0 = fmaf(winv[p], bfhi(u), h0);
    }
    alo[r] = l0 + l1; ahi[r] = h0 + h1;
  }
  const int c0 = cu * 2;
  if (V == 0) {
    float2 bv = *(const float2*)&bf[c0];
    #pragma unroll
    for (int r = 0; r < 4; ++r) { alo[r] *= bv.x; ahi[r] *= bv.y; }
  }
  u32* O32 = (u32*)Out;
  *(uint2*)&O32[(size_t)c0 * 1024 + (i0 >> 1)] =
      make_uint2(pack_bf16x2(alo[0], alo[1]), pack_bf16x2(alo[2], alo[3]));
  *(uint2*)&O32[(size_t)(c0 + 1) * 1024 + (i0 >> 1)] =
      make_uint2(pack_bf16x2(ahi[0], ahi[1]), pack_bf16x2(ahi[2], ahi[3]));
}

// ---------------------------------------------------------------- exp-domain sinkhorn iteration
// Block owns rows r0..r0+3 of P (bf16, LDS-staged).
// MODE 2: build P=exp(K-mu) w/o M (t==0); MODE 1: build with bf16 M; MODE 0: plain iter.
// Ai/Bj/RLi computed inline (Bj analytic since col-marginal == 1/N exactly).
// Row phase: a_i = 1/(N * sum_j P_ij b_j). Col phase: part[b][j] = sum_{4 rows} P_ij a_i.
template<int MODE>
__global__ __launch_bounds__(256) void k_iter(
    u32* __restrict__ P,
    const float* __restrict__ inter, const u32* __restrict__ M32,
    const int* __restrict__ rp1, const int* __restrict__ cols1, const float* __restrict__ vals1,
    const float* __restrict__ r1sq, const float* __restrict__ rs1,
    const float* __restrict__ r2sq, const float* __restrict__ rs2,
    const float* __restrict__ lamp, const float* __restrict__ asv_in,
    const float* __restrict__ bvec, float* __restrict__ avec,
    float* __restrict__ part) {
  __shared__ u32 Pl[4 * 1024];       // 16 KB: 4 rows x 2048 bf16
  __shared__ float bl[N];            // 8 KB
  __shared__ float a4[4];
  const int t = threadIdx.x;
  const int r0 = blockIdx.x * 4;
  const int w = t >> 6, lane = t & 63;
  const int row = r0 + w;

  if (MODE == 0) {
    #pragma unroll
    for (int q = 0; q < 2; ++q) {
      int j = (q * 256 + t) * 4;
      *(float4*)&bl[j] = *(const float4*)&bvec[j];
    }
    #pragma unroll
    for (int q = 0; q < 4; ++q) {
      int g = (q * 256 + t) * 4;
      *(uint4*)&Pl[g] = *(const uint4*)&P[(size_t)r0 * 1024 + g];
    }
    __syncthreads();
    float y = 0.f;
    const u32* Pr = Pl + w * 1024;
    #pragma unroll
    for (int k = 0; k < 16; ++k) {
      int g = lane + k * 64;
      u32 u = Pr[g];
      y = fmaf(bflo(u), bl[2 * g], y);
      y = fmaf(bfhi(u), bl[2 * g + 1], y);
    }
    for (int off = 32; off; off >>= 1) y += __shfl_xor(y, off);
    if (lane == 0) { float aw = 1.f / (2048.f * y); a4[w] = aw; avec[row] = aw; }
  } else {
    const float lam = *lamp;
    const float f = 0.00048828125f - lam * 2048.f;   // 1/2048 - 2048*lam
    float ai_, rli;
    if (MODE == 2) {
      ai_ = -2000.f * r1sq[row] * f;
      rli = 4000.f * rs1[row] * (2.384185791015625e-07f - lam);
    } else {
      int q0 = rp1[row], q1 = rp1[row + 1];
      float acc = 0.f;
      for (int p = q0 + lane; p < q1; p += 64) {
        float wv = vals1[p];
        acc = fmaf(wv * wv, asv_in[cols1[p]], acc);
      }
      for (int off = 32; off; off >>= 1) acc += __shfl_xor(acc, off);
      ai_ = -2000.f * (acc - lam * 2048.f * r1sq[row]);
      rli = -4000.f * lam * rs1[row];
    }
    const float bjf = -2000.f * f;
    float kv[32];
    float m = -INFINITY;
    const float* ir = inter + (size_t)row * N;
    const u32* mr = M32 + (size_t)row * 1024;
    #pragma unroll
    for (int q = 0; q < 8; ++q) {
      int j = lane * 4 + q * 256;
      float4 iv = *(const float4*)&ir[j];
      float4 rq = *(const float4*)&r2sq[j];
      float4 r2 = *(const float4*)&rs2[j];
      float k0 = fmaf(-100.f, iv.x, fmaf(bjf, rq.x, ai_ + rli * r2.x));
      float k1 = fmaf(-100.f, iv.y, fmaf(bjf, rq.y, ai_ + rli * r2.y));
      float k2 = fmaf(-100.f, iv.z, fmaf(bjf, rq.z, ai_ + rli * r2.z));
      float k3 = fmaf(-100.f, iv.w, fmaf(bjf, rq.w, ai_ + rli * r2.w));
      if (MODE == 1) {
        uint2 mu = *(const uint2*)&mr[j >> 1];
        k0 = fmaf(4000.f, bflo(mu.x), k0);
        k1 = fmaf(4000.f, bfhi(mu.x), k1);
        k2 = fmaf(4000.f, bflo(mu.y), k2);
        k3 = fmaf(4000.f, bfhi(mu.y), k3);
      }
      kv[q * 4 + 0] = k0; kv[q * 4 + 1] = k1; kv[q * 4 + 2] = k2; kv[q * 4 + 3] = k3;
      m = fmaxf(m, fmaxf(fmaxf(k0, k1), fmaxf(k2, k3)));
    }
    for (int off = 32; off; off >>= 1) m = fmaxf(m, __shfl_xor(m, off));
    float ss = 0.f;
    #pragma unroll
    for (int q = 0; q < 8; ++q) {
      float p0 = __expf(kv[q * 4 + 0] - m);
      float p1 = __expf(kv[q * 4 + 1] - m);
      float p2 = __expf(kv[q * 4 + 2] - m);
      float p3 = __expf(kv[q * 4 + 3] - m);
      ss += (p0 + p1) + (p2 + p3);
      u32 lo = pack_bf16x2(p0, p1), hi = pack_bf16x2(p2, p3);
      int g = lane * 2 + q * 128;
      Pl[w * 1024 + g] = lo; Pl[w * 1024 + g + 1] = hi;
      *(uint2*)&P[(size_t)row * 1024 + g] = make_uint2(lo, hi);
    }
    for (int off = 32; off; off >>= 1) ss += __shfl_xor(ss, off);
    if (lane == 0) { float aw = 1.f / (2048.f * ss); a4[w] = aw; avec[row] = aw; }
  }
  __syncthreads();
  const float a0 = a4[0], a1 = a4[1], a2 = a4[2], a3 = a4[3];
  #pragma unroll
  for (int k = 0; k < 4; ++k) {
    int g = k * 256 + t;
    u32 u0 = Pl[g], u1 = Pl[1024 + g], u2 = Pl[2048 + g], u3 = Pl[3072 + g];
    float zlo = bflo(u0) * a0 + bflo(u1) * a1 + bflo(u2) * a2 + bflo(u3) * a3;
    float zhi = bfhi(u0) * a0 + bfhi(u1) * a1 + bfhi(u2) * a2 + bfhi(u3) * a3;
    *(float2*)&part[(size_t)blockIdx.x * N + 2 * g] = make_float2(zlo, zhi);
  }
}

// combine 512 partials -> b = 1/(N*z). 128 blocks x 16 cols.
__global__ __launch_bounds__(256) void k_comb(const float* __restrict__ part, float* __restrict__ bvec) {
  __shared__ float pp[16][17];
  const int t = threadIdx.x;
  const int cl = t & 15, kg = t >> 4;
  const int c = blockIdx.x * 16 + cl;
  float z = 0.f;
  for (int k = kg * 32; k < kg * 32 + 32; ++k) z += part[(size_t)k * N + c];
  pp[kg][cl] = z;
  __syncthreads();
  if (t < 16) {
    float zz = 0.f;
    #pragma unroll
    for (int g = 0; g < 16; ++g) zz += pp[g][t];
    bvec[blockIdx.x * 16 + t] = 1.f / (2048.f * zz);
  }
}

// as_[i] = a_i * sum_j P_ij b_j  (final b of this outer iteration)
__global__ __launch_bounds__(256) void k_rowfin(const u32* __restrict__ P, const float* __restrict__ bvec,
                                                const float* __restrict__ avec, float* __restrict__ as_) {
  __shared__ float bl[N];
  const int t = threadIdx.x;
  #pragma unroll
  for (int q = 0; q < 2; ++q) {
    int j = (q * 256 + t) * 4;
    *(float4*)&bl[j] = *(const float4*)&bvec[j];
  }
  __syncthreads();
  const int w = t >> 6, lane = t & 63;
  const int row = blockIdx.x * 4 + w;
  const u32* Pr = P + (size_t)row * 1024;
  float y = 0.f;
  #pragma unroll
  for (int k = 0; k < 16; ++k) {
    int g = lane + k * 64;
    u32 u = Pr[g];
    y = fmaf(bflo(u), bl[2 * g], y);
    y = fmaf(bfhi(u), bl[2 * g + 1], y);
  }
  for (int off = 32; off; off >>= 1) y += __shfl_xor(y, off);
  if (lane == 0) as_[row] = avec[row] * y;
}

// ---------------------------------------------------------------- final

// final-only prep: paf = gather(w^2 * as), pbf = r2sq/N (col marginal exact)
__global__ __launch_bounds__(256) void k_prep2(
    const int* __restrict__ rp1, const int* __restrict__ cols1, const float* __restrict__ vals1,
    const float* __restrict__ r2sq, const float* __restrict__ as_,
    float* __restrict__ paf, float* __restrict__ pbf) {
  int g = blockIdx.x * 256 + threadIdx.x;
  if (g < N) {
    int p0 = rp1[g], p1 = rp1[g + 1];
    float acc = 0.f;
    for (int p = p0; p < p1; ++p) { float w = vals1[p]; acc = fmaf(w * w, as_[cols1[p]], acc); }
    paf[g] = acc;
  } else {
    int j = g - N;
    pbf[j] = r2sq[j] * 0.00048828125f;
  }
}

// s = a*P*b on the fly; writes s to output; sisr/yv row stats; dotp = partial of sum(M.*s)
__global__ __launch_bounds__(256) void k_fstats(
    const float* __restrict__ inter, const u32* __restrict__ P, const u32* __restrict__ M32,
    const float* __restrict__ rs2, const float* __restrict__ avec, const float* __restrict__ bvec,
    float* __restrict__ sOut, float* __restrict__ sisr, float* __restrict__ yv,
    double* __restrict__ dotp) {
  __shared__ __align__(16) float r2[N];
  __shared__ __align__(16) float bl[N];
  __shared__ double redm[4];
  const int t = threadIdx.x;
  #pragma unroll
  for (int q = 0; q < 2; ++q) {
    int j = (q * 256 + t) * 4;
    *(float4*)&r2[j] = *(const float4*)&rs2[j];
    *(float4*)&bl[j] = *(const float4*)&bvec[j];
  }
  __syncthreads();
  const int w = t >> 6, lane = t & 63;
  const int row = blockIdx.x * 4 + w;
  const float av = avec[row];
  const float* ir = inter + (size_t)row * N;
  const u32* mr = M32 + (size_t)row * 1024;
  const u32* Pr = P + (size_t)row * 1024;
  float* sr = sOut + (size_t)row * N;
  float d1 = 0.f, d2 = 0.f;
  double dm = 0.0;
  #pragma unroll 4
  for (int k = 0; k < 16; ++k) {
    int g = lane + k * 64;
    int j = 2 * g;
    u32 u = Pr[g];
    u32 mu = mr[g];
    float s0 = bflo(u) * av * bl[j];
    float s1 = bfhi(u) * av * bl[j + 1];
    float2 iv = *(const float2*)&ir[j];
    sr[j] = s0; sr[j + 1] = s1;
    d1 += iv.x * s0 + iv.y * s1;
    d2 += s0 * r2[j] + s1 * r2[j + 1];
    dm += (double)(bflo(mu) * s0) + (double)(bfhi(mu) * s1);
  }
  for (int off = 32; off; off >>= 1) {
    d1 += __shfl_down(d1, off);
    d2 += __shfl_down(d2, off);
    dm += __shfl_down(dm, off);
  }
  if (lane == 0) { sisr[row] = d1; yv[row] = d2; redm[w] = dm; }
  __syncthreads();
  if (t == 0) dotp[blockIdx.x] = redm[0] + redm[1] + redm[2] + redm[3];
}

__global__ __launch_bounds__(256) void k_final(
    const float* __restrict__ paf, const float* __restrict__ pbf,
    const float* __restrict__ r1sq, const float* __restrict__ r2sq,
    const float* __restrict__ rs1, const float* __restrict__ rs2,
    const float* __restrict__ as_,
    const float* __restrict__ yv, const float* __restrict__ sisr,
    const double* __restrict__ k1p, const double* __restrict__ dotp,
    const float* __restrict__ lamp, float* __restrict__ out_loss, float* __restrict__ out_lam) {
  __shared__ double red[256];
  int t = threadIdx.x;
  auto dred = [&](double acc) -> double {
    red[t] = acc; __syncthreads();
    for (int off = 128; off; off >>= 1) { if (t < off) red[t] += red[t + off]; __syncthreads(); }
    double r = red[0]; __syncthreads();
    return r;
  };
  auto dotv = [&](const float* a, const float* b) -> double {
    double acc = 0.0;
    for (int k = t; k < N; k += 256) acc += (double)a[k] * (b ? (double)b[k] : 1.0);
    return dred(acc);
  };
  double k1a = 0.0;
  for (int k = t; k < 1024; k += 256) k1a += k1p[k];
  double k1 = dred(k1a);
  double sma = 0.0;
  for (int k = t; k < 512; k += 256) sma += dotp[k];
  double smfs = dred(sma);
  double paas = dotv(paf, as_);
  double pbbs = dotv(pbf, nullptr) * (1.0 / 2048.0);
  double r1as = dotv(r1sq, as_);
  double rs1y = dotv(rs1, yv);
  double sis  = dotv(sisr, nullptr);
  double sr1  = dotv(r1sq, nullptr);
  double sr2  = dotv(r2sq, nullptr);
  double ss1  = dotv(rs1, nullptr);
  double ss2  = dotv(rs2, nullptr);
  if (t == 0) {
    double c2bs = sr2 / 2048.0;
    double lam0 = (double)*lamp;
    double k2 = 2048.0 * r1as + 2048.0 * c2bs - 2.0 * rs1y;
    double k3 = 2048.0 * 2048.0 * (sr1 + sr2) - 2.0 * ss1 * ss2;
    double upd = (k1 + 40.0 * k2) / (40.0 * k3);
    double lamn = 0.01 * upd + 0.99 * lam0;
    double g1 = paas + pbbs - 2.0 * smfs;
    double wl = sis - lamn * k1;
    double gwl = g1 - 2.0 * lamn * k2 + lamn * lamn * k3;
    double loss = wl + 20.0 * gwl + 20.0;
    *out_loss = (float)loss;
    *out_lam = (float)lamn;
  }
}

// ---------------------------------------------------------------- launch

extern "C" void kernel_launch(void* const* d_in, const int* in_sizes, int n_in,
                              void* d_out, int out_size, void* d_ws, size_t ws_size,
                              hipStream_t stream) {
  (void)in_sizes; (void)n_in; (void)out_size; (void)ws_size;
  const float* out1 = (const float*)d_in[0];
  const float* out2 = (const float*)d_in[1];
  const float* adj1 = (const float*)d_in[2];
  const float* adj2 = (const float*)d_in[3];
  const float* lamp = (const float*)d_in[4];
  float* o = (float*)d_out;
  float* sOut = o + 1;

  char* w = (char*)d_ws;
  size_t off = 0;
  auto alloc = [&](size_t bytes) -> void* {
    void* p = w + off;
    off = (off + bytes + 255) & ~(size_t)255;
    return p;
  };
  const size_t NNf = (size_t)N * N * sizeof(float);
  float* inter = (float*)alloc(NNf);
  u32*  Pbuf   = (u32*)alloc((size_t)N * 1024 * sizeof(u32));   // bf16x2 packed
  u16*  Tth    = (u16*)alloc((size_t)N * N * sizeof(u16));      // bf16
  u16*  Mb16   = (u16*)alloc((size_t)N * N * sizeof(u16));      // bf16 M
  int* rp1   = (int*)alloc((N + 1) * sizeof(int));
  int* rp2   = (int*)alloc((N + 1) * sizeof(int));
  int* cnt   = (int*)alloc(N * sizeof(int));
  int* cols1 = (int*)alloc(CAP * sizeof(int));
  int* rows1 = (int*)alloc(CAP * sizeof(int));
  int* cols2 = (int*)alloc(CAP * sizeof(int));
  int* rows2 = (int*)alloc(CAP * sizeof(int));
  float* vals1 = (float*)alloc(CAP * sizeof(float));
  float* vals2 = (float*)alloc(CAP * sizeof(float));
  float* r1sq = (float*)alloc(N * sizeof(float));
  float* rs1  = (float*)alloc(N * sizeof(float));
  float* r2sq = (float*)alloc(N * sizeof(float));
  float* rs2v = (float*)alloc(N * sizeof(float));
  float* asv  = (float*)alloc(N * sizeof(float));
  float* avec = (float*)alloc(N * sizeof(float));
  float* bvec = (float*)alloc(N * sizeof(float));
  float* yv   = (float*)alloc(N * sizeof(float));
  float* sisr = (float*)alloc(N * sizeof(float));
  float* paf  = (float*)alloc(N * sizeof(float));
  float* pbf  = (float*)alloc(N * sizeof(float));
  float* part = (float*)alloc((size_t)512 * N * sizeof(float));
  double* k1p = (double*)alloc(1024 * sizeof(double));
  double* dotp= (double*)alloc(512 * sizeof(double));

  dim3 b(256);

  // ---- precompute
  k_gemm_inter<<<dim3(32, 32), b, 0, stream>>>(out1, out2, inter, k1p);
  k_count<<<512, b, 0, stream>>>(adj1, cnt);
  k_scan<<<1, b, 0, stream>>>(cnt, rp1);
  k_count<<<512, b, 0, stream>>>(adj2, cnt);
  k_scan<<<1, b, 0, stream>>>(cnt, rp2);
  k_fill<<<512, b, 0, stream>>>(adj1, rp1, cols1, rows1);
  k_fill<<<512, b, 0, stream>>>(adj2, rp2, cols2, rows2);
  k_vals<<<2048, b, 0, stream>>>(rp1, rows1, cols1, vals1, out1);
  k_vals<<<2048, b, 0, stream>>>(rp2, rows2, cols2, vals2, out2);
  k_rowstats<<<512, b, 0, stream>>>(rp1, vals1, rs1, r1sq);
  k_rowstats<<<512, b, 0, stream>>>(rp2, vals2, rs2v, r2sq);

  // ---- outer loop
  for (int t = 0; t < 10; ++t) {
    if (t > 0) {
      k_spmmt<0><<<2048, b, 0, stream>>>(rp1, cols1, vals1, Pbuf, avec, bvec, Tth);
      k_spmmt<1><<<2048, b, 0, stream>>>(rp2, cols2, vals2, (const u32*)Tth, nullptr, nullptr, Mb16);
      k_iter<1><<<512, b, 0, stream>>>(Pbuf, inter, (const u32*)Mb16, rp1, cols1, vals1,
                                       r1sq, rs1, r2sq, rs2v, lamp, asv, bvec, avec, part);
    } else {
      k_iter<2><<<512, b, 0, stream>>>(Pbuf, inter, (const u32*)Mb16, rp1, cols1, vals1,
                                       r1sq, rs1, r2sq, rs2v, lamp, asv, bvec, avec, part);
    }
    k_comb<<<128, b, 0, stream>>>(part, bvec);
    for (int r = 1; r < 5; ++r) {
      k_iter<0><<<512, b, 0, stream>>>(Pbuf, inter, (const u32*)Mb16, rp1, cols1, vals1,
                                       r1sq, rs1, r2sq, rs2v, lamp, asv, bvec, avec, part);
      k_comb<<<128, b, 0, stream>>>(part, bvec);
    }
    k_rowfin<<<512, b, 0, stream>>>(Pbuf, bvec, avec, asv);
  }

  // ---- final: lambda update + loss
  k_spmmt<0><<<2048, b, 0, stream>>>(rp1, cols1, vals1, Pbuf, avec, bvec, Tth);
  k_spmmt<1><<<2048, b, 0, stream>>>(rp2, cols2, vals2, (const u32*)Tth, nullptr, nullptr, Mb16);
  k_prep2<<<16, b, 0, stream>>>(rp1, cols1, vals1, r2sq, asv, paf, pbf);
  k_fstats<<<512, b, 0, stream>>>(inter, Pbuf, (const u32*)Mb16, rs2v, avec, bvec, sOut, sisr, yv, dotp);
  k_final<<<1, b, 0, stream>>>(paf, pbf, r1sq, r2sq, rs1, rs2v, asv, yv, sisr,
                               k1p, dotp, lamp, o, o + 1 + (size_t)N * N);
}

// Round 10
// 989.304 us; speedup vs baseline: 2.2039x; 1.0484x over previous
//
#include <hip/hip_runtime.h>
#include <math.h>

#define N 2048
#define DIM 128
#define CAP (N*64)

typedef unsigned long long u64;
typedef unsigned int u32;
typedef unsigned short u16;

__device__ __forceinline__ u32 bf16bits(float f) {
  u32 x = __float_as_uint(f);
  return (x + 0x7fffu + ((x >> 16) & 1u)) >> 16;
}
__device__ __forceinline__ u32 pack_bf16x2(float lo, float hi) {
  return bf16bits(lo) | (bf16bits(hi) << 16);
}
__device__ __forceinline__ float bflo(u32 u) { return __uint_as_float(u << 16); }
__device__ __forceinline__ float bfhi(u32 u) { return __uint_as_float(u & 0xffff0000u); }

// ---------------------------------------------------------------- precompute

// inter = exp(-(A @ B^T)): store bf16 inter (Ib) and bf16 E = exp(100 - 100*inter) (Eb);
// per-block partial sums of inter -> k1p (fp64, exact k1).
__global__ __launch_bounds__(256) void k_gemm_inter(
    const float* __restrict__ A, const float* __restrict__ B,
    u16* __restrict__ Ib, u16* __restrict__ Eb, double* __restrict__ k1p) {
  __shared__ __align__(16) float As[64][65];
  __shared__ __align__(16) float Bs[64][65];
  __shared__ float red[256];
  const int t = threadIdx.x;
  const int i0 = blockIdx.y * 64, j0 = blockIdx.x * 64;
  const int tx = t & 15, ty = t >> 4;
  float acc[4][4] = {};
  for (int kk = 0; kk < DIM; kk += 64) {
    if (kk) __syncthreads();
    for (int q = t; q < 64 * 16; q += 256) {
      int row = q >> 4, k4 = (q & 15) << 2;
      float4 av = *(const float4*)&A[(size_t)(i0 + row) * DIM + kk + k4];
      As[k4 + 0][row] = av.x; As[k4 + 1][row] = av.y;
      As[k4 + 2][row] = av.z; As[k4 + 3][row] = av.w;
      float4 bv = *(const float4*)&B[(size_t)(j0 + row) * DIM + kk + k4];
      Bs[k4 + 0][row] = bv.x; Bs[k4 + 1][row] = bv.y;
      Bs[k4 + 2][row] = bv.z; Bs[k4 + 3][row] = bv.w;
    }
    __syncthreads();
    #pragma unroll 4
    for (int k = 0; k < 64; ++k) {
      float av[4], bv[4];
      #pragma unroll
      for (int d = 0; d < 4; ++d) { av[d] = As[k][ty * 4 + d]; bv[d] = Bs[k][tx * 4 + d]; }
      #pragma unroll
      for (int di = 0; di < 4; ++di)
        #pragma unroll
        for (int dj = 0; dj < 4; ++dj)
          acc[di][dj] = fmaf(av[di], bv[dj], acc[di][dj]);
    }
  }
  float psum = 0.f;
  #pragma unroll
  for (int di = 0; di < 4; ++di) {
    float iv[4], ev[4];
    #pragma unroll
    for (int dj = 0; dj < 4; ++dj) {
      iv[dj] = __expf(-acc[di][dj]);
      ev[dj] = __expf(fmaf(-100.f, iv[dj], 100.f));
      psum += iv[dj];
    }
    size_t base = (size_t)(i0 + ty * 4 + di) * N + (j0 + tx * 4);
    *(uint2*)&Ib[base] = make_uint2(pack_bf16x2(iv[0], iv[1]), pack_bf16x2(iv[2], iv[3]));
    *(uint2*)&Eb[base] = make_uint2(pack_bf16x2(ev[0], ev[1]), pack_bf16x2(ev[2], ev[3]));
  }
  red[t] = psum; __syncthreads();
  for (int off = 128; off; off >>= 1) { if (t < off) red[t] += red[t + off]; __syncthreads(); }
  if (t == 0) k1p[blockIdx.y * 32 + blockIdx.x] = (double)red[0];
}

// both adjacency matrices in one launch: blocks <512 -> adj1, else adj2
__global__ __launch_bounds__(256) void k_count2(const float* __restrict__ adj1, const float* __restrict__ adj2,
                                                int* __restrict__ cnt1, int* __restrict__ cnt2) {
  int half = blockIdx.x >> 9;
  const float* adj = half ? adj2 : adj1;
  int* cnt = half ? cnt2 : cnt1;
  int i = (blockIdx.x & 511) * 4 + (threadIdx.x >> 6);
  int lane = threadIdx.x & 63;
  const float* row = adj + (size_t)i * N;
  int c = 0;
  for (int j = lane; j < N; j += 64) c += (row[j] != 0.f) ? 1 : 0;
  for (int off = 32; off; off >>= 1) c += __shfl_down(c, off);
  if (lane == 0) cnt[i] = c;
}

__global__ __launch_bounds__(256) void k_scan2(const int* __restrict__ cnt1, const int* __restrict__ cnt2,
                                               int* __restrict__ rp1, int* __restrict__ rp2) {
  const int* cnt = blockIdx.x ? cnt2 : cnt1;
  int* rp = blockIdx.x ? rp2 : rp1;
  __shared__ int sums[256];
  int t = threadIdx.x;
  int local[8]; int run = 0;
  int base = t * 8;
  #pragma unroll
  for (int k = 0; k < 8; ++k) { local[k] = run; run += cnt[base + k]; }
  sums[t] = run; __syncthreads();
  for (int off = 1; off < 256; off <<= 1) {
    int val = (t >= off) ? sums[t - off] : 0;
    __syncthreads();
    sums[t] += val;
    __syncthreads();
  }
  int pre = (t == 0) ? 0 : sums[t - 1];
  #pragma unroll
  for (int k = 0; k < 8; ++k) rp[base + k] = pre + local[k];
  if (t == 255) rp[N] = sums[255];
}

__global__ __launch_bounds__(256) void k_fill2(const float* __restrict__ adj1, const float* __restrict__ adj2,
                                               const int* __restrict__ rp1, const int* __restrict__ rp2,
                                               int* __restrict__ cols1, int* __restrict__ rows1,
                                               int* __restrict__ cols2, int* __restrict__ rows2) {
  int half = blockIdx.x >> 9;
  const float* adj = half ? adj2 : adj1;
  const int* rp = half ? rp2 : rp1;
  int* cols = half ? cols2 : cols1;
  int* rows = half ? rows2 : rows1;
  int i = (blockIdx.x & 511) * 4 + (threadIdx.x >> 6);
  int lane = threadIdx.x & 63;
  const float* row = adj + (size_t)i * N;
  int pos = rp[i];
  for (int j0 = 0; j0 < N; j0 += 64) {
    bool p = row[j0 + lane] != 0.f;
    u64 mask = __ballot(p);
    if (p) {
      int off = __popcll(mask & ((1ull << lane) - 1ull));
      cols[pos + off] = j0 + lane;
      rows[pos + off] = i;
    }
    pos += __popcll(mask);
  }
}

__global__ __launch_bounds__(256) void k_vals2(
    const int* __restrict__ rp1, const int* __restrict__ rows1, const int* __restrict__ cols1,
    float* __restrict__ vals1, const float* __restrict__ emb1,
    const int* __restrict__ rp2, const int* __restrict__ rows2, const int* __restrict__ cols2,
    float* __restrict__ vals2, const float* __restrict__ emb2) {
  int half = blockIdx.x >> 10;
  const int* rp = half ? rp2 : rp1;
  const int* rows = half ? rows2 : rows1;
  const int* cols = half ? cols2 : cols1;
  float* vals = half ? vals2 : vals1;
  const float* emb = half ? emb2 : emb1;
  int lane = threadIdx.x & 63;
  int total = rp[N];
  for (int p = (blockIdx.x & 1023) * 4 + (threadIdx.x >> 6); p < total; p += 4096) {
    int i = rows[p], k = cols[p];
    const float* ei = emb + (size_t)i * DIM;
    const float* ek = emb + (size_t)k * DIM;
    float s = ei[lane] * ek[lane] + ei[lane + 64] * ek[lane + 64];
    for (int off = 32; off; off >>= 1) s += __shfl_down(s, off);
    if (lane == 0) vals[p] = __expf(-s);
  }
}

__global__ __launch_bounds__(256) void k_rowstats2(
    const int* __restrict__ rp1, const float* __restrict__ vals1,
    float* __restrict__ rs1, float* __restrict__ rsq1,
    const int* __restrict__ rp2, const float* __restrict__ vals2,
    float* __restrict__ rs2, float* __restrict__ rsq2) {
  int half = blockIdx.x >> 9;
  const int* rp = half ? rp2 : rp1;
  const float* vals = half ? vals2 : vals1;
  float* rs = half ? rs2 : rs1;
  float* rsq = half ? rsq2 : rsq1;
  int i = (blockIdx.x & 511) * 4 + (threadIdx.x >> 6);
  int lane = threadIdx.x & 63;
  int p0 = rp[i], p1 = rp[i + 1];
  float s1 = 0.f, s2 = 0.f;
  for (int p = p0 + lane; p < p1; p += 64) { float w = vals[p]; s1 += w; s2 += w * w; }
  for (int off = 32; off; off >>= 1) { s1 += __shfl_down(s1, off); s2 += __shfl_down(s2, off); }
  if (lane == 0) { rs[i] = s1; rsq[i] = s2; }
}

// ---------------------------------------------------------------- spmm (bf16 u32-pair gather)
// V=0: S = P; weights folded with af[col]; output cols scaled by bf; Out = Tt (bf16).
//      FIN=1: blocks >= 2048 run rowfin: asv[row] = af[row] * sum_j P[row,j]*bf[j].
// V=1: S = Tt; plain weights; Out = M (bf16).
template<int V, int FIN>
__global__ __launch_bounds__(256) void k_spmmt(const int* __restrict__ rp, const int* __restrict__ cols,
                                               const float* __restrict__ vals, const u32* __restrict__ S,
                                               const float* __restrict__ af, const float* __restrict__ bf,
                                               u16* __restrict__ Out, float* __restrict__ asv) {
  __shared__ int winc[512];
  __shared__ float winv[512];
  __shared__ int rb[5];
  __shared__ float blf[N];
  const int t = threadIdx.x;
  if (FIN && blockIdx.x >= 2048) {
    // rowfin: as_[row] = a_row * sum_j P[row,j] * b[j]
    #pragma unroll
    for (int q = 0; q < 2; ++q) {
      int j = (q * 256 + t) * 4;
      *(float4*)&blf[j] = *(const float4*)&bf[j];
    }
    __syncthreads();
    const int w = t >> 6, lane = t & 63;
    const int row = (blockIdx.x - 2048) * 4 + w;
    const u32* Pr = S + (size_t)row * 1024;
    float y = 0.f;
    #pragma unroll
    for (int k = 0; k < 16; ++k) {
      int g = lane + k * 64;
      u32 u = Pr[g];
      y = fmaf(bflo(u), blf[2 * g], y);
      y = fmaf(bfhi(u), blf[2 * g + 1], y);
    }
    for (int off = 32; off; off >>= 1) y += __shfl_xor(y, off);
    if (lane == 0) asv[row] = af[row] * y;
    return;
  }
  const int tile = blockIdx.x & 3;
  const int cu = tile * 256 + t;            // u32 col index (2 u16 cols)
  const int i0 = (blockIdx.x >> 2) * 4;
  const int p0 = rp[i0];
  if (t < 5) rb[t] = rp[i0 + t] - p0;
  __syncthreads();
  const int nn = rb[4];
  for (int k = t; k < nn; k += 256) {
    int col = cols[p0 + k];
    winc[k] = col << 10;                    // * 1024 u32 row stride
    winv[k] = (V == 0) ? vals[p0 + k] * af[col] : vals[p0 + k];
  }
  __syncthreads();
  float alo[4], ahi[4];
  #pragma unroll
  for (int r = 0; r < 4; ++r) {
    int pe = rb[r + 1], p = rb[r];
    float l0 = 0.f, l1 = 0.f, h0 = 0.f, h1 = 0.f;
    for (; p + 1 < pe; p += 2) {
      u32 u0 = S[winc[p] + cu], u1 = S[winc[p + 1] + cu];
      l0 = fmaf(winv[p],     bflo(u0), l0);  h0 = fmaf(winv[p],     bfhi(u0), h0);
      l1 = fmaf(winv[p + 1], bflo(u1), l1);  h1 = fmaf(winv[p + 1], bfhi(u1), h1);
    }
    if (p < pe) {
      u32 u = S[winc[p] + cu];
      l0 = fmaf(winv[p], bflo(u), l0);  h0 = fmaf(winv[p], bfhi(u), h0);
    }
    alo[r] = l0 + l1; ahi[r] = h0 + h1;
  }
  const int c0 = cu * 2;
  if (V == 0) {
    float2 bv = *(const float2*)&bf[c0];
    #pragma unroll
    for (int r = 0; r < 4; ++r) { alo[r] *= bv.x; ahi[r] *= bv.y; }
  }
  u32* O32 = (u32*)Out;
  *(uint2*)&O32[(size_t)c0 * 1024 + (i0 >> 1)] =
      make_uint2(pack_bf16x2(alo[0], alo[1]), pack_bf16x2(alo[2], alo[3]));
  *(uint2*)&O32[(size_t)(c0 + 1) * 1024 + (i0 >> 1)] =
      make_uint2(pack_bf16x2(ahi[0], ahi[1]), pack_bf16x2(ahi[2], ahi[3]));
}

// ---------------------------------------------------------------- exp-domain sinkhorn iteration
// P~ = E * exp(Ai + bjf*r2sq + rli*rs2 [+ 4000*M]) — no row-max needed (global +100 shift
// inside E keeps the bf16/fp32 exponent range; Sinkhorn a,b absorb scale exactly).
// MODE 2: build (t==0, analytic Ai/RLi); MODE 1: build with bf16 M + Ai gather; MODE 0: plain.
// Row phase: a_i = 1/(N * sum_j P_ij b_j)  (build: b = 1). Col phase: partials.
template<int MODE>
__global__ __launch_bounds__(256) void k_iter(
    u32* __restrict__ P,
    const u32* __restrict__ E32, const u32* __restrict__ M32,
    const int* __restrict__ rp1, const int* __restrict__ cols1, const float* __restrict__ vals1,
    const float* __restrict__ r1sq, const float* __restrict__ rs1,
    const float* __restrict__ r2sq, const float* __restrict__ rs2,
    const float* __restrict__ lamp, const float* __restrict__ asv_in,
    const float* __restrict__ bvec, float* __restrict__ avec,
    float* __restrict__ part) {
  __shared__ u32 Pl[4 * 1024];       // 16 KB: 4 rows x 2048 bf16
  __shared__ float bl[N];            // 8 KB
  __shared__ float a4[4];
  const int t = threadIdx.x;
  const int r0 = blockIdx.x * 4;
  const int w = t >> 6, lane = t & 63;
  const int row = r0 + w;

  if (MODE == 0) {
    #pragma unroll
    for (int q = 0; q < 2; ++q) {
      int j = (q * 256 + t) * 4;
      *(float4*)&bl[j] = *(const float4*)&bvec[j];
    }
    #pragma unroll
    for (int q = 0; q < 4; ++q) {
      int g = (q * 256 + t) * 4;
      *(uint4*)&Pl[g] = *(const uint4*)&P[(size_t)r0 * 1024 + g];
    }
    __syncthreads();
    float y = 0.f;
    const u32* Pr = Pl + w * 1024;
    #pragma unroll
    for (int k = 0; k < 16; ++k) {
      int g = lane + k * 64;
      u32 u = Pr[g];
      y = fmaf(bflo(u), bl[2 * g], y);
      y = fmaf(bfhi(u), bl[2 * g + 1], y);
    }
    for (int off = 32; off; off >>= 1) y += __shfl_xor(y, off);
    if (lane == 0) { float aw = 1.f / (2048.f * y); a4[w] = aw; avec[row] = aw; }
  } else {
    const float lam = *lamp;
    const float f = 0.00048828125f - lam * 2048.f;   // 1/2048 - 2048*lam
    float ai_, rli;
    if (MODE == 2) {
      ai_ = -2000.f * r1sq[row] * f;
      rli = 4000.f * rs1[row] * (2.384185791015625e-07f - lam);
    } else {
      int q0 = rp1[row], q1 = rp1[row + 1];
      float acc = 0.f;
      for (int p = q0 + lane; p < q1; p += 64) {
        float wv = vals1[p];
        acc = fmaf(wv * wv, asv_in[cols1[p]], acc);
      }
      for (int off = 32; off; off >>= 1) acc += __shfl_xor(acc, off);
      ai_ = -2000.f * (acc - lam * 2048.f * r1sq[row]);
      rli = -4000.f * lam * rs1[row];
    }
    const float bjf = -2000.f * f;
    float ss = 0.f;
    const u32* er = E32 + (size_t)row * 1024;
    const u32* mr = M32 + (size_t)row * 1024;
    #pragma unroll
    for (int q = 0; q < 8; ++q) {
      int j = lane * 4 + q * 256;
      uint2 eu = *(const uint2*)&er[j >> 1];
      float4 rq = *(const float4*)&r2sq[j];
      float4 r2 = *(const float4*)&rs2[j];
      float d0 = fmaf(bjf, rq.x, fmaf(rli, r2.x, ai_));
      float d1 = fmaf(bjf, rq.y, fmaf(rli, r2.y, ai_));
      float d2 = fmaf(bjf, rq.z, fmaf(rli, r2.z, ai_));
      float d3 = fmaf(bjf, rq.w, fmaf(rli, r2.w, ai_));
      if (MODE == 1) {
        uint2 mu = *(const uint2*)&mr[j >> 1];
        d0 = fmaf(4000.f, bflo(mu.x), d0);
        d1 = fmaf(4000.f, bfhi(mu.x), d1);
        d2 = fmaf(4000.f, bflo(mu.y), d2);
        d3 = fmaf(4000.f, bfhi(mu.y), d3);
      }
      float p0 = bflo(eu.x) * __expf(d0);
      float p1 = bfhi(eu.x) * __expf(d1);
      float p2 = bflo(eu.y) * __expf(d2);
      float p3 = bfhi(eu.y) * __expf(d3);
      ss += (p0 + p1) + (p2 + p3);
      u32 lo = pack_bf16x2(p0, p1), hi = pack_bf16x2(p2, p3);
      int g = lane * 2 + q * 128;
      Pl[w * 1024 + g] = lo; Pl[w * 1024 + g + 1] = hi;
      *(uint2*)&P[(size_t)row * 1024 + g] = make_uint2(lo, hi);
    }
    for (int off = 32; off; off >>= 1) ss += __shfl_xor(ss, off);
    if (lane == 0) { float aw = 1.f / (2048.f * ss); a4[w] = aw; avec[row] = aw; }
  }
  __syncthreads();
  const float a0 = a4[0], a1 = a4[1], a2 = a4[2], a3 = a4[3];
  #pragma unroll
  for (int k = 0; k < 4; ++k) {
    int g = k * 256 + t;
    u32 u0 = Pl[g], u1 = Pl[1024 + g], u2 = Pl[2048 + g], u3 = Pl[3072 + g];
    float zlo = bflo(u0) * a0 + bflo(u1) * a1 + bflo(u2) * a2 + bflo(u3) * a3;
    float zhi = bfhi(u0) * a0 + bfhi(u1) * a1 + bfhi(u2) * a2 + bfhi(u3) * a3;
    *(float2*)&part[(size_t)blockIdx.x * N + 2 * g] = make_float2(zlo, zhi);
  }
}

// combine 512 partials -> b = 1/(N*z). 128 blocks x 16 cols.
__global__ __launch_bounds__(256) void k_comb(const float* __restrict__ part, float* __restrict__ bvec) {
  __shared__ float pp[16][17];
  const int t = threadIdx.x;
  const int cl = t & 15, kg = t >> 4;
  const int c = blockIdx.x * 16 + cl;
  float z = 0.f;
  for (int k = kg * 32; k < kg * 32 + 32; ++k) z += part[(size_t)k * N + c];
  pp[kg][cl] = z;
  __syncthreads();
  if (t < 16) {
    float zz = 0.f;
    #pragma unroll
    for (int g = 0; g < 16; ++g) zz += pp[g][t];
    bvec[blockIdx.x * 16 + t] = 1.f / (2048.f * zz);
  }
}

// ---------------------------------------------------------------- final

// blocks <512: s = a*P*b on the fly -> sOut; row stats sisr/yv; dotp partials of sum(M.*s).
// blocks >=512 (16 blocks): prep2 -> paf (CSR gather of w^2*as), pbf = r2sq/N.
__global__ __launch_bounds__(256) void k_fstats(
    const u32* __restrict__ Ib, const u32* __restrict__ P, const u32* __restrict__ M32,
    const float* __restrict__ rs2, const float* __restrict__ avec, const float* __restrict__ bvec,
    float* __restrict__ sOut, float* __restrict__ sisr, float* __restrict__ yv,
    double* __restrict__ dotp,
    const int* __restrict__ rp1, const int* __restrict__ cols1, const float* __restrict__ vals1,
    const float* __restrict__ r2sq, const float* __restrict__ asv,
    float* __restrict__ paf, float* __restrict__ pbf) {
  const int t = threadIdx.x;
  if (blockIdx.x >= 512) {
    int g = (blockIdx.x - 512) * 256 + t;
    if (g < N) {
      int p0 = rp1[g], p1 = rp1[g + 1];
      float acc = 0.f;
      for (int p = p0; p < p1; ++p) { float w = vals1[p]; acc = fmaf(w * w, asv[cols1[p]], acc); }
      paf[g] = acc;
    } else {
      int j = g - N;
      pbf[j] = r2sq[j] * 0.00048828125f;
    }
    return;
  }
  __shared__ __align__(16) float r2[N];
  __shared__ __align__(16) float bl[N];
  __shared__ double redm[4];
  #pragma unroll
  for (int q = 0; q < 2; ++q) {
    int j = (q * 256 + t) * 4;
    *(float4*)&r2[j] = *(const float4*)&rs2[j];
    *(float4*)&bl[j] = *(const float4*)&bvec[j];
  }
  __syncthreads();
  const int w = t >> 6, lane = t & 63;
  const int row = blockIdx.x * 4 + w;
  const float av = avec[row];
  const u32* ir = Ib + (size_t)row * 1024;
  const u32* mr = M32 + (size_t)row * 1024;
  const u32* Pr = P + (size_t)row * 1024;
  float* sr = sOut + (size_t)row * N;
  float d1 = 0.f, d2 = 0.f;
  double dm = 0.0;
  #pragma unroll 4
  for (int k = 0; k < 16; ++k) {
    int g = lane + k * 64;
    int j = 2 * g;
    u32 u = Pr[g];
    u32 mu = mr[g];
    u32 iu = ir[g];
    float s0 = bflo(u) * av * bl[j];
    float s1 = bfhi(u) * av * bl[j + 1];
    sr[j] = s0; sr[j + 1] = s1;
    d1 += bflo(iu) * s0 + bfhi(iu) * s1;
    d2 += s0 * r2[j] + s1 * r2[j + 1];
    dm += (double)(bflo(mu) * s0) + (double)(bfhi(mu) * s1);
  }
  for (int off = 32; off; off >>= 1) {
    d1 += __shfl_down(d1, off);
    d2 += __shfl_down(d2, off);
    dm += __shfl_down(dm, off);
  }
  if (lane == 0) { sisr[row] = d1; yv[row] = d2; redm[w] = dm; }
  __syncthreads();
  if (t == 0) dotp[blockIdx.x] = redm[0] + redm[1] + redm[2] + redm[3];
}

__global__ __launch_bounds__(256) void k_final(
    const float* __restrict__ paf, const float* __restrict__ pbf,
    const float* __restrict__ r1sq, const float* __restrict__ r2sq,
    const float* __restrict__ rs1, const float* __restrict__ rs2,
    const float* __restrict__ as_,
    const float* __restrict__ yv, const float* __restrict__ sisr,
    const double* __restrict__ k1p, const double* __restrict__ dotp,
    const float* __restrict__ lamp, float* __restrict__ out_loss, float* __restrict__ out_lam) {
  __shared__ double red[256];
  int t = threadIdx.x;
  auto dred = [&](double acc) -> double {
    red[t] = acc; __syncthreads();
    for (int off = 128; off; off >>= 1) { if (t < off) red[t] += red[t + off]; __syncthreads(); }
    double r = red[0]; __syncthreads();
    return r;
  };
  auto dotv = [&](const float* a, const float* b) -> double {
    double acc = 0.0;
    for (int k = t; k < N; k += 256) acc += (double)a[k] * (b ? (double)b[k] : 1.0);
    return dred(acc);
  };
  double k1a = 0.0;
  for (int k = t; k < 1024; k += 256) k1a += k1p[k];
  double k1 = dred(k1a);
  double sma = 0.0;
  for (int k = t; k < 512; k += 256) sma += dotp[k];
  double smfs = dred(sma);
  double paas = dotv(paf, as_);
  double pbbs = dotv(pbf, nullptr) * (1.0 / 2048.0);
  double r1as = dotv(r1sq, as_);
  double rs1y = dotv(rs1, yv);
  double sis  = dotv(sisr, nullptr);
  double sr1  = dotv(r1sq, nullptr);
  double sr2  = dotv(r2sq, nullptr);
  double ss1  = dotv(rs1, nullptr);
  double ss2  = dotv(rs2, nullptr);
  if (t == 0) {
    double c2bs = sr2 / 2048.0;
    double lam0 = (double)*lamp;
    double k2 = 2048.0 * r1as + 2048.0 * c2bs - 2.0 * rs1y;
    double k3 = 2048.0 * 2048.0 * (sr1 + sr2) - 2.0 * ss1 * ss2;
    double upd = (k1 + 40.0 * k2) / (40.0 * k3);
    double lamn = 0.01 * upd + 0.99 * lam0;
    double g1 = paas + pbbs - 2.0 * smfs;
    double wl = sis - lamn * k1;
    double gwl = g1 - 2.0 * lamn * k2 + lamn * lamn * k3;
    double loss = wl + 20.0 * gwl + 20.0;
    *out_loss = (float)loss;
    *out_lam = (float)lamn;
  }
}

// ---------------------------------------------------------------- launch

extern "C" void kernel_launch(void* const* d_in, const int* in_sizes, int n_in,
                              void* d_out, int out_size, void* d_ws, size_t ws_size,
                              hipStream_t stream) {
  (void)in_sizes; (void)n_in; (void)out_size; (void)ws_size;
  const float* out1 = (const float*)d_in[0];
  const float* out2 = (const float*)d_in[1];
  const float* adj1 = (const float*)d_in[2];
  const float* adj2 = (const float*)d_in[3];
  const float* lamp = (const float*)d_in[4];
  float* o = (float*)d_out;
  float* sOut = o + 1;

  char* w = (char*)d_ws;
  size_t off = 0;
  auto alloc = [&](size_t bytes) -> void* {
    void* p = w + off;
    off = (off + bytes + 255) & ~(size_t)255;
    return p;
  };
  u16*  Ib     = (u16*)alloc((size_t)N * N * sizeof(u16));      // bf16 inter
  u16*  Eb     = (u16*)alloc((size_t)N * N * sizeof(u16));      // bf16 exp(100-100*inter)
  u32*  Pbuf   = (u32*)alloc((size_t)N * 1024 * sizeof(u32));   // bf16x2 packed
  u16*  Tth    = (u16*)alloc((size_t)N * N * sizeof(u16));      // bf16
  u16*  Mb16   = (u16*)alloc((size_t)N * N * sizeof(u16));      // bf16 M
  int* rp1   = (int*)alloc((N + 1) * sizeof(int));
  int* rp2   = (int*)alloc((N + 1) * sizeof(int));
  int* cnt1  = (int*)alloc(N * sizeof(int));
  int* cnt2  = (int*)alloc(N * sizeof(int));
  int* cols1 = (int*)alloc(CAP * sizeof(int));
  int* rows1 = (int*)alloc(CAP * sizeof(int));
  int* cols2 = (int*)alloc(CAP * sizeof(int));
  int* rows2 = (int*)alloc(CAP * sizeof(int));
  float* vals1 = (float*)alloc(CAP * sizeof(float));
  float* vals2 = (float*)alloc(CAP * sizeof(float));
  float* r1sq = (float*)alloc(N * sizeof(float));
  float* rs1  = (float*)alloc(N * sizeof(float));
  float* r2sq = (float*)alloc(N * sizeof(float));
  float* rs2v = (float*)alloc(N * sizeof(float));
  float* asv  = (float*)alloc(N * sizeof(float));
  float* avec = (float*)alloc(N * sizeof(float));
  float* bvec = (float*)alloc(N * sizeof(float));
  float* yv   = (float*)alloc(N * sizeof(float));
  float* sisr = (float*)alloc(N * sizeof(float));
  float* paf  = (float*)alloc(N * sizeof(float));
  float* pbf  = (float*)alloc(N * sizeof(float));
  float* part = (float*)alloc((size_t)512 * N * sizeof(float));
  double* k1p = (double*)alloc(1024 * sizeof(double));
  double* dotp= (double*)alloc(512 * sizeof(double));

  dim3 b(256);

  // ---- precompute
  k_gemm_inter<<<dim3(32, 32), b, 0, stream>>>(out1, out2, Ib, Eb, k1p);
  k_count2<<<1024, b, 0, stream>>>(adj1, adj2, cnt1, cnt2);
  k_scan2<<<2, b, 0, stream>>>(cnt1, cnt2, rp1, rp2);
  k_fill2<<<1024, b, 0, stream>>>(adj1, adj2, rp1, rp2, cols1, rows1, cols2, rows2);
  k_vals2<<<2048, b, 0, stream>>>(rp1, rows1, cols1, vals1, out1, rp2, rows2, cols2, vals2, out2);
  k_rowstats2<<<1024, b, 0, stream>>>(rp1, vals1, rs1, r1sq, rp2, vals2, rs2v, r2sq);

  // ---- outer loop
  for (int t = 0; t < 10; ++t) {
    if (t > 0) {
      // spmmt<0> also carries rowfin for outer t-1 (blocks >= 2048)
      k_spmmt<0, 1><<<2560, b, 0, stream>>>(rp1, cols1, vals1, Pbuf, avec, bvec, Tth, asv);
      k_spmmt<1, 0><<<2048, b, 0, stream>>>(rp2, cols2, vals2, (const u32*)Tth, nullptr, nullptr, Mb16, nullptr);
      k_iter<1><<<512, b, 0, stream>>>(Pbuf, (const u32*)Eb, (const u32*)Mb16, rp1, cols1, vals1,
                                       r1sq, rs1, r2sq, rs2v, lamp, asv, bvec, avec, part);
    } else {
      k_iter<2><<<512, b, 0, stream>>>(Pbuf, (const u32*)Eb, (const u32*)Mb16, rp1, cols1, vals1,
                                       r1sq, rs1, r2sq, rs2v, lamp, asv, bvec, avec, part);
    }
    k_comb<<<128, b, 0, stream>>>(part, bvec);
    for (int r = 1; r < 5; ++r) {
      k_iter<0><<<512, b, 0, stream>>>(Pbuf, (const u32*)Eb, (const u32*)Mb16, rp1, cols1, vals1,
                                       r1sq, rs1, r2sq, rs2v, lamp, asv, bvec, avec, part);
      k_comb<<<128, b, 0, stream>>>(part, bvec);
    }
  }

  // ---- final: lambda update + loss (spmmt<0> carries rowfin for t=9)
  k_spmmt<0, 1><<<2560, b, 0, stream>>>(rp1, cols1, vals1, Pbuf, avec, bvec, Tth, asv);
  k_spmmt<1, 0><<<2048, b, 0, stream>>>(rp2, cols2, vals2, (const u32*)Tth, nullptr, nullptr, Mb16, nullptr);
  k_fstats<<<528, b, 0, stream>>>((const u32*)Ib, Pbuf, (const u32*)Mb16, rs2v, avec, bvec,
                                  sOut, sisr, yv, dotp, rp1, cols1, vals1, r2sq, asv, paf, pbf);
  k_final<<<1, b, 0, stream>>>(paf, pbf, r1sq, r2sq, rs1, rs2v, asv, yv, sisr,
                               k1p, dotp, lamp, o, o + 1 + (size_t)N * N);
}